// Round 20
// baseline (1037.607 us; speedup 1.0000x reference)
//
#include <hip/hip_runtime.h>
#include <hip/hip_bf16.h>

typedef unsigned short u16;
typedef unsigned int   u32;
typedef unsigned long long u64;
typedef __attribute__((ext_vector_type(8))) short short8;   // 8 x bf16 (4 VGPRs)
typedef __attribute__((ext_vector_type(4))) float f32x4;

#define DEVINL static __device__ __forceinline__

// round-to-nearest-even f32 -> bf16
DEVINL u16 f2bf(float x) {
  u32 u = __float_as_uint(x);
  u32 r = (u + 0x7fffu + ((u >> 16) & 1u)) >> 16;
  return (u16)r;
}

// async global->LDS, 16B per lane. LDS dest = uniform base + lane*16.
#define GLD16(gp, lp) __builtin_amdgcn_global_load_lds(                     \
    (const __attribute__((address_space(1))) u32*)(gp),                     \
    (__attribute__((address_space(3))) u32*)(lp), 16, 0, 0)

// ---------------------------------------------------------------------------
// fp32 -> bf16 bulk convert, the four 4Kx1K weight tensors in one launch.
__global__ __launch_bounds__(256) void conv4(
    const float* __restrict__ s0, u16* __restrict__ d0,
    const float* __restrict__ s1, u16* __restrict__ d1,
    const float* __restrict__ s2, u16* __restrict__ d2,
    const float* __restrict__ s3, u16* __restrict__ d3) {
  int blk = blockIdx.x;
  int p = blk >> 12, local = blk & 4095;
  const float* s = (p == 0) ? s0 : (p == 1) ? s1 : (p == 2) ? s2 : s3;
  u16*         d = (p == 0) ? d0 : (p == 1) ? d1 : (p == 2) ? d2 : d3;
  int i = local * 256 + threadIdx.x;
  float4 v = ((const float4*)s)[i];
  ushort4 o;
  o.x = f2bf(v.x); o.y = f2bf(v.y); o.z = f2bf(v.z); o.w = f2bf(v.w);
  ((ushort4*)d)[i] = o;
}

// standalone W_out conversion (fallback path only)
__global__ __launch_bounds__(256) void conv_wout(const float* __restrict__ s,
                                                 u16* __restrict__ d) {
  int i = blockIdx.x * 256 + threadIdx.x;
  float4 v = ((const float4*)s)[i];
  ushort4 o;
  o.x = f2bf(v.x); o.y = f2bf(v.y); o.z = f2bf(v.z); o.w = f2bf(v.w);
  ((ushort4*)d)[i] = o;
}

// cond_e gather + fused bias vectors + zero barrier state
__global__ __launch_bounds__(256) void prep_small(
    const int* __restrict__ cond, const float* __restrict__ emb_cond,
    const float* __restrict__ bihN, const float* __restrict__ bhhN,
    const float* __restrict__ bihD, const float* __restrict__ bhhD,
    float* __restrict__ ce, float* __restrict__ biasN, float* __restrict__ biasD,
    u32* __restrict__ bar) {
  int tid = blockIdx.x * 256 + threadIdx.x;
  if (tid < 512) {
    int b = tid >> 3, j = tid & 7;
    ce[tid] = emb_cond[cond[b] * 8 + j];
  }
  int i = tid - 512;
  if (i >= 0 && i < 4096) {
    biasN[i] = bihN[i] + bhhN[i];
    biasD[i] = bihD[i] + bhhD[i];
  }
  int k = tid - 4608;
  if (k >= 0 && k < 1024) bar[k] = 0;
}

// encoder h0 = [zeros(B,1016), cond_e] -> bf16 into hbuf[0]
__global__ __launch_bounds__(256) void init_enc(const float* __restrict__ ce,
                                                u16* __restrict__ hb0) {
  int tid = blockIdx.x * 256 + threadIdx.x;   // 64*1024
  int b = tid >> 10, col = tid & 1023;
  float v = (col >= 1016) ? ce[b * 8 + (col - 1016)] : 0.f;
  hb0[tid] = f2bf(v);
}

// embedding row gather -> bf16, X[t*64+b][1024]
__global__ __launch_bounds__(256) void gather_kernel(const float* __restrict__ emb,
                                                     const int* __restrict__ words,
                                                     u16* __restrict__ X, int dec) {
  int r = blockIdx.x;                    // r = t*64 + b
  int t = r >> 6, b = r & 63;
  int tok = dec ? ((t == 0) ? 0 : words[b * 64 + t - 1]) : words[b * 64 + t];
  float4 v = ((const float4*)(emb + (size_t)tok * 1024))[threadIdx.x];
  ushort4 o;
  o.x = f2bf(v.x); o.y = f2bf(v.y); o.z = f2bf(v.z); o.w = f2bf(v.w);
  ((ushort4*)(X + (size_t)r * 1024))[threadIdx.x] = o;
}

// ---------------------------------------------------------------------------
// GEMM body, MODE-0 style (n-fast + bijective XCD swizzle), 256x128 tile,
// BK=32, 512 threads = 8 waves (4m x 2n), double-buffered LDS (48KB).
DEVINL void gemm0_body(char* smemc, int bid, int nwg,
                       const u16* __restrict__ A, const u16* __restrict__ B,
                       float* __restrict__ C, const float* __restrict__ bias,
                       int N, int K) {
  u16 (*lA)[256 * 32] = (u16(*)[256 * 32])smemc;
  u16 (*lB)[128 * 32] = (u16(*)[128 * 32])(smemc + 32768);
  const int tid = threadIdx.x;
  const int lane = tid & 63;
  const int wid = tid >> 6;

  const int nn = N >> 7;
  const int wgid = (bid & 7) * (nwg >> 3) + (bid >> 3);
  const int tile_m = (wgid / nn) * 256;
  const int tile_n = (wgid % nn) * 128;
  const int wm = wid >> 1, wn = wid & 1;

  const int ldr = lane >> 2;
  const int lko = (lane & 3) * 8;
  const int l15 = lane & 15;
  const int g4 = lane >> 4;

  const size_t aBase = (size_t)tile_m * K;
  const size_t bBase = (size_t)tile_n * K;

  auto stage = [&](int buf, int k0) {
#pragma unroll
    for (int q = 0; q < 2; ++q) {
      int chk = wid * 2 + q;
      int row = chk * 16 + ldr;
      GLD16(A + aBase + (size_t)row * K + k0 + lko, &lA[buf][chk * 512]);
    }
    int row = wid * 16 + ldr;
    GLD16(B + bBase + (size_t)row * K + k0 + lko, &lB[buf][wid * 512]);
  };

  f32x4 acc[4][4];
#pragma unroll
  for (int i = 0; i < 4; ++i)
#pragma unroll
    for (int j = 0; j < 4; ++j) acc[i][j] = (f32x4)0.f;

  stage(0, 0);
  __syncthreads();

  const int NIT = K >> 5;
  for (int it = 0; it < NIT; ++it) {
    const int cur = it & 1;
    if (it + 1 < NIT) stage(cur ^ 1, (it + 1) * 32);
    short8 af[4], bf[4];
#pragma unroll
    for (int i = 0; i < 4; ++i)
      af[i] = *(const short8*)&lA[cur][(wm * 64 + i * 16 + l15) * 32 + g4 * 8];
#pragma unroll
    for (int j = 0; j < 4; ++j)
      bf[j] = *(const short8*)&lB[cur][(wn * 64 + j * 16 + l15) * 32 + g4 * 8];
#pragma unroll
    for (int i = 0; i < 4; ++i)
#pragma unroll
      for (int j = 0; j < 4; ++j)
        acc[i][j] = __builtin_amdgcn_mfma_f32_16x16x32_bf16(af[i], bf[j], acc[i][j], 0, 0, 0);
    __syncthreads();
  }

#pragma unroll
  for (int i = 0; i < 4; ++i) {
    int row0 = tile_m + wm * 64 + i * 16 + (g4 << 2);
#pragma unroll
    for (int j = 0; j < 4; ++j) {
      int col = tile_n + wn * 64 + j * 16 + l15;
      float bv = bias[col];
#pragma unroll
      for (int e = 0; e < 4; ++e)
        C[(size_t)(row0 + e) * (size_t)N + col] = acc[i][j][e] + bv;
    }
  }
}

// ---------------------------------------------------------------------------
// CLUSTERED PERSISTENT LSTM body (r15/r16-proven skeleton). hs_out (decoder)
// is T-MAJOR ([t*64+b][1024]), written via packed-u32 agent-atomic stores.
DEVINL void lstm_body(char* smemc, const u16* __restrict__ Whh,
                      const float* __restrict__ Xp, u16* __restrict__ hbuf,
                      u16* __restrict__ hs_out, float* __restrict__ hT_out,
                      u32* arrive, int wgi) {
  char* smemA = smemc;
  float (*lg)[16][16] = (float(*)[16][16])(smemc + 32768);
  const int tid = threadIdx.x;      // 0..511
  const int lane = tid & 63;
  const int v = tid >> 6;           // wave 0..7
  const int gate = v >> 1;
  const int ch = v & 1;             // col-half of the WG's 32 cols
  const int c = wgi >> 5;           // cluster 0..3 (batch rows c*16..+16)
  const int j = wgi & 31;           // WG in cluster (cols j*32..+32)
  const int b0 = c * 16, col0 = j * 32;
  const int l15 = lane & 15, g4 = lane >> 4;

  // Whh fragments: loaded ONCE, live across all 64 steps (128 VGPRs)
  short8 breg[32];
  {
    const u16* Brow = Whh + (size_t)(gate * 1024 + col0 + ch * 16 + l15) * 1024
                          + g4 * 8;
#pragma unroll
    for (int kk = 0; kk < 32; ++kk)
      breg[kk] = *(const short8*)(Brow + kk * 32);
  }

  // cell mapping: 512 threads = 16 rows x 32 cols
  const int crow = tid >> 5, colw = tid & 31;
  const int bg = b0 + crow, cgl = col0 + colw;
  const int ch2 = colw >> 4, cw = colw & 15;
  float creg = 0.f;

  // prologue: Xp prefetch for t=0
  float xg0, xg1, xg2, xg3;
  {
    size_t xrow = (size_t)bg * 4096 + cgl;
    xg0 = __builtin_nontemporal_load(&Xp[xrow]);
    xg1 = __builtin_nontemporal_load(&Xp[xrow + 1024]);
    xg2 = __builtin_nontemporal_load(&Xp[xrow + 2048]);
    xg3 = __builtin_nontemporal_load(&Xp[xrow + 3072]);
  }

  for (int t = 0; t < 64; ++t) {
    const char* rbase = (const char*)(hbuf + (size_t)(t & 1) * 65536)
                      + (size_t)b0 * 2048;
    u32* wb32 = (u32*)(hbuf + (size_t)((t + 1) & 1) * 65536);

    // ---- stage h slab (16 rows x 1024 cols) -> swizzled LDS, atomic loads
#pragma unroll
    for (int q = 0; q < 4; ++q) {
      int g = q * 512 + tid;              // 16B chunk id 0..2047
      int row = g >> 7;                   // 0..15
      int cb = (g & 127) * 16;            // byte col in row
      const u64* src = (const u64*)(rbase + (size_t)row * 2048 + cb);
      u64 lo = __hip_atomic_load(src,     __ATOMIC_RELAXED, __HIP_MEMORY_SCOPE_AGENT);
      u64 hi = __hip_atomic_load(src + 1, __ATOMIC_RELAXED, __HIP_MEMORY_SCOPE_AGENT);
      u64* d = (u64*)(smemA + row * 2048 + (cb ^ ((row & 7) << 4)));
      d[0] = lo; d[1] = hi;
    }
    __syncthreads();

    // ---- 32 MFMAs/wave (4 chains), A from swizzled LDS, B from regs
    f32x4 a4[4] = {(f32x4)0.f, (f32x4)0.f, (f32x4)0.f, (f32x4)0.f};
#pragma unroll
    for (int kk = 0; kk < 32; ++kk) {
      int cb2 = kk * 64 + g4 * 16;
      const short8 a = *(const short8*)(smemA + l15 * 2048 + (cb2 ^ ((l15 & 7) << 4)));
      a4[kk & 3] = __builtin_amdgcn_mfma_f32_16x16x32_bf16(a, breg[kk], a4[kk & 3], 0, 0, 0);
    }
    f32x4 asum = a4[0] + a4[1] + a4[2] + a4[3];
    {
      int m = g4 * 4;
#pragma unroll
      for (int e = 0; e < 4; ++e) lg[v][m + e][l15] = asum[e];
    }
    __syncthreads();

    // ---- cell update: 1 cell per thread (uses prefetched xg)
    {
      float gi = lg[0 + ch2][crow][cw] + xg0;
      float gf = lg[2 + ch2][crow][cw] + xg1;
      float gg = lg[4 + ch2][crow][cw] + xg2;
      float go = lg[6 + ch2][crow][cw] + xg3;
      float si = 1.f / (1.f + __expf(-gi));
      float sf = 1.f / (1.f + __expf(-gf));
      float so = 1.f / (1.f + __expf(-go));
      float tg = tanhf(gg);
      float cn = sf * creg + si * tg;
      float hn = so * tanhf(cn);
      creg = cn;
      u16 h16 = f2bf(hn);
      u32 mine = h16;
      u32 other = (u32)__shfl_xor((int)mine, 1);
      if (!(colw & 1)) {
        u32 pk = mine | (other << 16);
        __hip_atomic_store(wb32 + (((size_t)bg * 1024 + cgl) >> 1), pk,
                           __ATOMIC_RELAXED, __HIP_MEMORY_SCOPE_AGENT);
        if (hs_out)   // t-major ([t*64+b][1024]), consumed by next kernel
          __hip_atomic_store((u32*)hs_out + ((((size_t)t * 64 + bg) * 1024 + cgl) >> 1),
                             pk, __ATOMIC_RELAXED, __HIP_MEMORY_SCOPE_AGENT);
      }
      if (hT_out && t == 63) hT_out[bg * 1024 + cgl] = hn;   // cross-kernel
    }

    // ---- prefetch next-step Xp, then flat fence-free cluster barrier
    if (t != 63) {
      {
        size_t xrow = (size_t)((t + 1) * 64 + bg) * 4096 + cgl;
        xg0 = __builtin_nontemporal_load(&Xp[xrow]);
        xg1 = __builtin_nontemporal_load(&Xp[xrow + 1024]);
        xg2 = __builtin_nontemporal_load(&Xp[xrow + 2048]);
        xg3 = __builtin_nontemporal_load(&Xp[xrow + 3072]);
      }
      u32 want = (u32)(t + 1);
      asm volatile("s_waitcnt vmcnt(0)" ::: "memory");   // drains h/hsd stores + Xp
      __syncthreads();
      if (tid == 0)
        __hip_atomic_store(&arrive[wgi], want, __ATOMIC_RELAXED,
                           __HIP_MEMORY_SCOPE_AGENT);
      if (tid < 32) {
        int guard = 0;
        while (__hip_atomic_load(&arrive[c * 32 + tid], __ATOMIC_RELAXED,
                                 __HIP_MEMORY_SCOPE_AGENT) < want) {
          __builtin_amdgcn_s_sleep(2);
          if (++guard > (1 << 20)) break;   // safety valve
        }
      }
      __syncthreads();
    }
  }
}

// ---------------------------------------------------------------------------
// Standalone LSTM wrapper (encoder fallback + decoder).
__global__ __launch_bounds__(512, 1) void lstm_cluster(
    const u16* __restrict__ Whh, const float* __restrict__ Xp,
    u16* __restrict__ hbuf, u16* __restrict__ hs_out,
    float* __restrict__ hT_out, u32* arrive) {
  __shared__ __align__(16) char smem[40960];
  lstm_body(smem, Whh, Xp, hbuf, hs_out, hT_out, arrive, blockIdx.x);
}

__global__ __launch_bounds__(512) void gemm_bt0(
    const u16* __restrict__ A, const u16* __restrict__ B,
    float* __restrict__ C, const float* __restrict__ bias, int N, int K) {
  __shared__ __align__(16) char smem[49152];
  gemm0_body(smem, blockIdx.x, gridDim.x, A, B, C, bias, N, K);
}

// Fused encoder: blocks 0..127 = encoder LSTM (co-resident); 128..639 =
// decoder-Xp GEMM; 640..1151 = W_out fp32->bf16 conversion (grid-stride).
__global__ __launch_bounds__(512, 1) void enc_fused(
    const u16* __restrict__ whhN, const float* __restrict__ XpE,
    u16* __restrict__ hbuf, float* __restrict__ hT_out, u32* arrive,
    const u16* __restrict__ Xd, const u16* __restrict__ wihD,
    float* __restrict__ XpD, const float* __restrict__ biasD,
    const float* __restrict__ Wout, u16* __restrict__ wout) {
  __shared__ __align__(16) char smem[49152];
  if (blockIdx.x < 128) {
    lstm_body(smem, whhN, XpE, hbuf, nullptr, hT_out, arrive, blockIdx.x);
  } else if (blockIdx.x < 640) {
    gemm0_body(smem, blockIdx.x - 128, 512, Xd, wihD, XpD, biasD, 4096, 1024);
  } else {
    int tid0 = (blockIdx.x - 640) * 512 + threadIdx.x;
    for (int i = tid0; i < 8192000; i += 512 * 512) {
      float4 v = ((const float4*)Wout)[i];
      ushort4 o;
      o.x = f2bf(v.x); o.y = f2bf(v.y); o.z = f2bf(v.z); o.w = f2bf(v.w);
      ((ushort4*)wout)[i] = o;
    }
  }
}

// ---------------------------------------------------------------------------
// Logits GEMM (standalone, serial after decoder LSTM): A = hsd T-MAJOR
// [t*64+b][1024], per-XCD n-partition, 2-phase dbuf, REMAP NT stores
// out[b*64+t][col].
__global__ __launch_bounds__(512) void gemm_bt1(
    const u16* __restrict__ hsd, const u16* __restrict__ wout,
    float* __restrict__ out, const float* __restrict__ b_out) {
  __shared__ u16 lA[2][256 * 32];
  __shared__ u16 lB[2][128 * 32];
  const int tid = threadIdx.x;
  const int lane = tid & 63;
  const int wid = tid >> 6;

  const int i = blockIdx.x;        // 0..4095
  const int x = i & 7;             // XCD id
  const int k = i >> 3;
  const int mg = k >> 6;
  const int r  = k & 63;
  const int kn = r >> 1;
  const int mi = r & 1;
  const int tn = kn * 8 + x;
  if (tn >= 250) return;           // dummy (whole WG exits)
  const int tile_m = (mg * 2 + mi) * 256;
  const int tile_n = tn * 128;
  const int wm = wid >> 1, wn = wid & 1;
  const int N = 32000, K = 1024;

  const int ldr = lane >> 2;
  const int lko = (lane & 3) * 8;
  const int l15 = lane & 15;
  const int g4 = lane >> 4;

  const size_t aBase = (size_t)tile_m * K;
  const size_t bBase = (size_t)tile_n * K;

  auto stg = [&](int buf, int k0) {
#pragma unroll
    for (int q = 0; q < 2; ++q) {
      int chk = wid * 2 + q;
      int row = chk * 16 + ldr;
      GLD16(hsd + aBase + (size_t)row * K + k0 + lko, &lA[buf][chk * 512]);
    }
    int row = wid * 16 + ldr;
    GLD16(wout + bBase + (size_t)row * K + k0 + lko, &lB[buf][wid * 512]);
  };

  f32x4 acc[4][4];
#pragma unroll
  for (int i2 = 0; i2 < 4; ++i2)
#pragma unroll
    for (int j2 = 0; j2 < 4; ++j2) acc[i2][j2] = (f32x4)0.f;

  stg(0, 0);
  __syncthreads();

  const int NIT = K >> 5;
  for (int it = 0; it < NIT; ++it) {
    const int cur = it & 1;
    if (it + 1 < NIT) stg(cur ^ 1, (it + 1) * 32);
    short8 af[4], bf[4];
#pragma unroll
    for (int i2 = 0; i2 < 4; ++i2)
      af[i2] = *(const short8*)&lA[cur][(wm * 64 + i2 * 16 + l15) * 32 + g4 * 8];
#pragma unroll
    for (int j2 = 0; j2 < 4; ++j2)
      bf[j2] = *(const short8*)&lB[cur][(wn * 64 + j2 * 16 + l15) * 32 + g4 * 8];
#pragma unroll
    for (int i2 = 0; i2 < 4; ++i2)
#pragma unroll
      for (int j2 = 0; j2 < 4; ++j2)
        acc[i2][j2] = __builtin_amdgcn_mfma_f32_16x16x32_bf16(af[i2], bf[j2], acc[i2][j2], 0, 0, 0);
    __syncthreads();
  }

#pragma unroll
  for (int i2 = 0; i2 < 4; ++i2) {
    int row0 = tile_m + wm * 64 + i2 * 16 + (g4 << 2);
#pragma unroll
    for (int j2 = 0; j2 < 4; ++j2) {
      int col = tile_n + wn * 64 + j2 * 16 + l15;
      float bv = b_out[col];
#pragma unroll
      for (int e = 0; e < 4; ++e) {
        int rr = row0 + e;                       // t-major row = t*64+b
        size_t o = (size_t)((rr & 63) * 64 + (rr >> 6)) * (size_t)N + col;
        __builtin_nontemporal_store(acc[i2][j2][e] + bv, &out[o]);
      }
    }
  }
}

// ---------------------------------------------------------------------------
// mean/logvar/latent + hd0 = [latent|cond_e] @ W_st^T + b_st -> bf16 h0.
__global__ __launch_bounds__(256) void latent_hd0_kernel(
    const float* hT, const float* Wm, const float* bm,
    const float* Wl, const float* bl, const float* Wst, const float* bst,
    const float* eps, const float* ce, u16* hb0) {
  __shared__ float red[64][4];
  __shared__ float ml[64];
  __shared__ float lat[40];
  int b = blockIdx.x;
  int tid = threadIdx.x;
  int o = tid >> 2, p = tid & 3;
  const float* w = (o < 32) ? (Wm + (size_t)o * 1024) : (Wl + (size_t)(o - 32) * 1024);
  const float* h = hT + (size_t)b * 1024;
  float s = 0.f;
  for (int k = p * 256; k < p * 256 + 256; ++k) s += h[k] * w[k];
  red[o][p] = s;
  __syncthreads();
  if (tid < 64) {
    float v = red[tid][0] + red[tid][1] + red[tid][2] + red[tid][3];
    v += (tid < 32) ? bm[tid] : bl[tid - 32];
    ml[tid] = v;
  }
  __syncthreads();
  if (tid < 32) lat[tid] = eps[b * 32 + tid] * __expf(0.5f * ml[32 + tid]) + ml[tid];
  if (tid >= 32 && tid < 40) lat[tid] = ce[b * 8 + (tid - 32)];
  __syncthreads();
  for (int hc = tid; hc < 1024; hc += 256) {
    float s2 = bst[hc];
    const float* wr = Wst + (size_t)hc * 40;
#pragma unroll
    for (int j = 0; j < 40; ++j) s2 += lat[j] * wr[j];
    hb0[b * 1024 + hc] = f2bf(s2);
  }
}

// ---------------------------------------------------------------------------
extern "C" void kernel_launch(void* const* d_in, const int* in_sizes, int n_in,
                              void* d_out, int out_size, void* d_ws, size_t ws_size,
                              hipStream_t stream) {
  const int*   input_word = (const int*)d_in[0];
  const int*   cond       = (const int*)d_in[1];
  const float* emb_N      = (const float*)d_in[2];
  const float* Wih_N      = (const float*)d_in[3];
  const float* Whh_N      = (const float*)d_in[4];
  const float* bih_N      = (const float*)d_in[5];
  const float* bhh_N      = (const float*)d_in[6];
  const float* emb_D      = (const float*)d_in[7];
  const float* Wih_D      = (const float*)d_in[8];
  const float* Whh_D      = (const float*)d_in[9];
  const float* bih_D      = (const float*)d_in[10];
  const float* bhh_D      = (const float*)d_in[11];
  const float* emb_cond   = (const float*)d_in[12];
  const float* W_mean     = (const float*)d_in[13];
  const float* b_mean     = (const float*)d_in[14];
  const float* W_logvar   = (const float*)d_in[15];
  const float* b_logvar   = (const float*)d_in[16];
  const float* W_st       = (const float*)d_in[17];
  const float* b_st       = (const float*)d_in[18];
  const float* W_out      = (const float*)d_in[19];
  const float* b_out      = (const float*)d_in[20];
  const float* eps        = (const float*)d_in[21];
  float* out = (float*)d_out;

  char* ws = (char*)d_ws;
  size_t off = 0;
  auto alloc = [&](size_t b) { size_t p = off; off += (b + 255) & ~(size_t)255; return p; };
  u16*   wihN = (u16*)(ws + alloc(4096ull * 1024 * 2));
  u16*   whhN = (u16*)(ws + alloc(4096ull * 1024 * 2));
  u16*   wihD = (u16*)(ws + alloc(4096ull * 1024 * 2));
  u16*   whhD = (u16*)(ws + alloc(4096ull * 1024 * 2));
  u16*   wout = (u16*)(ws + alloc(32000ull * 1024 * 2));
  u16*   Xe   = (u16*)(ws + alloc(4096ull * 1024 * 2));
  u16*   Xd   = (u16*)(ws + alloc(4096ull * 1024 * 2));
  float* Xp   = (float*)(ws + alloc(4096ull * 4096 * 4));   // enc (and dec fallback)
  u16*   hsd  = (u16*)(ws + alloc(4096ull * 1024 * 2));     // T-MAJOR [t*64+b][1024]
  u16*   hb   = (u16*)(ws + alloc(2ull * 64 * 1024 * 2));   // bf16 h dbuf
  float* hf   = (float*)(ws + alloc(64ull * 1024 * 4));     // fp32 h_T (encoder)
  float* biasN = (float*)(ws + alloc(4096 * 4));
  float* biasD = (float*)(ws + alloc(4096 * 4));
  float* ce    = (float*)(ws + alloc(64 * 8 * 4));
  u32*   bar   = (u32*)(ws + alloc(4096));
  // bar: enc arrive [0..127], dec arrive [256..383]
  size_t base_off = off;
  float* XpD2 = (float*)(ws + alloc(4096ull * 4096 * 4));   // dec Xp (fused path)
  if (base_off > ws_size) return;
  const bool fused = (off <= ws_size);
  float* XpD = fused ? XpD2 : Xp;

  conv4<<<16384, 256, 0, stream>>>(Wih_N, wihN, Whh_N, whhN,
                                   Wih_D, wihD, Whh_D, whhD);
  prep_small<<<22, 256, 0, stream>>>(cond, emb_cond, bih_N, bhh_N, bih_D, bhh_D,
                                     ce, biasN, biasD, bar);
  gather_kernel<<<4096, 256, 0, stream>>>(emb_N, input_word, Xe, 0);
  gather_kernel<<<4096, 256, 0, stream>>>(emb_D, input_word, Xd, 1);
  init_enc<<<256, 256, 0, stream>>>(ce, hb);

  // encoder Xp
  gemm_bt0<<<512, 512, 0, stream>>>(Xe, wihN, Xp, biasN, 4096, 1024);
  if (fused) {
    // encoder LSTM + decoder-Xp GEMM + W_out conversion, one launch
    enc_fused<<<1152, 512, 0, stream>>>(whhN, Xp, hb, hf, bar + 0,
                                        Xd, wihD, XpD, biasD, W_out, wout);
  } else {
    conv_wout<<<32000, 256, 0, stream>>>(W_out, wout);
    lstm_cluster<<<128, 512, 0, stream>>>(whhN, Xp, hb, nullptr, hf, bar + 0);
  }
  // latent + decoder h0
  latent_hd0_kernel<<<64, 256, 0, stream>>>(hf, W_mean, b_mean, W_logvar, b_logvar,
                                            W_st, b_st, eps, ce, hb);
  if (!fused)
    gemm_bt0<<<512, 512, 0, stream>>>(Xd, wihD, XpD, biasD, 4096, 1024);
  // decoder LSTM (serial) -> t-major hsd
  lstm_cluster<<<128, 512, 0, stream>>>(whhD, XpD, hb, hsd, nullptr, bar + 256);
  // logits GEMM (serial): out[b*64+t] = hsd[t*64+b] @ W_out^T + b_out
  gemm_bt1<<<4096, 512, 0, stream>>>(hsd, wout, out, b_out);
}

// Round 21
// 1029.686 us; speedup vs baseline: 1.0077x; 1.0077x over previous
//
#include <hip/hip_runtime.h>
#include <hip/hip_bf16.h>

typedef unsigned short u16;
typedef unsigned int   u32;
typedef unsigned long long u64;
typedef __attribute__((ext_vector_type(8))) short short8;   // 8 x bf16 (4 VGPRs)
typedef __attribute__((ext_vector_type(4))) float f32x4;

#define DEVINL static __device__ __forceinline__

// round-to-nearest-even f32 -> bf16
DEVINL u16 f2bf(float x) {
  u32 u = __float_as_uint(x);
  u32 r = (u + 0x7fffu + ((u >> 16) & 1u)) >> 16;
  return (u16)r;
}

// async global->LDS, 16B per lane. LDS dest = uniform base + lane*16.
#define GLD16(gp, lp) __builtin_amdgcn_global_load_lds(                     \
    (const __attribute__((address_space(1))) u32*)(gp),                     \
    (__attribute__((address_space(3))) u32*)(lp), 16, 0, 0)

// ---------------------------------------------------------------------------
// fp32 -> bf16 bulk convert, the four 4Kx1K weight tensors in one launch.
__global__ __launch_bounds__(256) void conv4(
    const float* __restrict__ s0, u16* __restrict__ d0,
    const float* __restrict__ s1, u16* __restrict__ d1,
    const float* __restrict__ s2, u16* __restrict__ d2,
    const float* __restrict__ s3, u16* __restrict__ d3) {
  int blk = blockIdx.x;
  int p = blk >> 12, local = blk & 4095;
  const float* s = (p == 0) ? s0 : (p == 1) ? s1 : (p == 2) ? s2 : s3;
  u16*         d = (p == 0) ? d0 : (p == 1) ? d1 : (p == 2) ? d2 : d3;
  int i = local * 256 + threadIdx.x;
  float4 v = ((const float4*)s)[i];
  ushort4 o;
  o.x = f2bf(v.x); o.y = f2bf(v.y); o.z = f2bf(v.z); o.w = f2bf(v.w);
  ((ushort4*)d)[i] = o;
}

// standalone W_out conversion (fallback path only)
__global__ __launch_bounds__(256) void conv_wout(const float* __restrict__ s,
                                                 u16* __restrict__ d) {
  int i = blockIdx.x * 256 + threadIdx.x;
  float4 v = ((const float4*)s)[i];
  ushort4 o;
  o.x = f2bf(v.x); o.y = f2bf(v.y); o.z = f2bf(v.z); o.w = f2bf(v.w);
  ((ushort4*)d)[i] = o;
}

// cond_e gather + fused bias vectors + zero barrier state
__global__ __launch_bounds__(256) void prep_small(
    const int* __restrict__ cond, const float* __restrict__ emb_cond,
    const float* __restrict__ bihN, const float* __restrict__ bhhN,
    const float* __restrict__ bihD, const float* __restrict__ bhhD,
    float* __restrict__ ce, float* __restrict__ biasN, float* __restrict__ biasD,
    u32* __restrict__ bar) {
  int tid = blockIdx.x * 256 + threadIdx.x;
  if (tid < 512) {
    int b = tid >> 3, j = tid & 7;
    ce[tid] = emb_cond[cond[b] * 8 + j];
  }
  int i = tid - 512;
  if (i >= 0 && i < 4096) {
    biasN[i] = bihN[i] + bhhN[i];
    biasD[i] = bihD[i] + bhhD[i];
  }
  int k = tid - 4608;
  if (k >= 0 && k < 1024) bar[k] = 0;
}

// encoder h0 = [zeros(B,1016), cond_e] -> bf16 into hbuf[0]
__global__ __launch_bounds__(256) void init_enc(const float* __restrict__ ce,
                                                u16* __restrict__ hb0) {
  int tid = blockIdx.x * 256 + threadIdx.x;   // 64*1024
  int b = tid >> 10, col = tid & 1023;
  float v = (col >= 1016) ? ce[b * 8 + (col - 1016)] : 0.f;
  hb0[tid] = f2bf(v);
}

// embedding row gather -> bf16, X[t*64+b][1024]
__global__ __launch_bounds__(256) void gather_kernel(const float* __restrict__ emb,
                                                     const int* __restrict__ words,
                                                     u16* __restrict__ X, int dec) {
  int r = blockIdx.x;                    // r = t*64 + b
  int t = r >> 6, b = r & 63;
  int tok = dec ? ((t == 0) ? 0 : words[b * 64 + t - 1]) : words[b * 64 + t];
  float4 v = ((const float4*)(emb + (size_t)tok * 1024))[threadIdx.x];
  ushort4 o;
  o.x = f2bf(v.x); o.y = f2bf(v.y); o.z = f2bf(v.z); o.w = f2bf(v.w);
  ((ushort4*)(X + (size_t)r * 1024))[threadIdx.x] = o;
}

// ---------------------------------------------------------------------------
// GEMM body, MODE-0 style (n-fast + bijective XCD swizzle), 256x128 tile,
// BK=32, 512 threads = 8 waves (4m x 2n), double-buffered LDS (48KB).
DEVINL void gemm0_body(char* smemc, int bid, int nwg,
                       const u16* __restrict__ A, const u16* __restrict__ B,
                       float* __restrict__ C, const float* __restrict__ bias,
                       int N, int K) {
  u16 (*lA)[256 * 32] = (u16(*)[256 * 32])smemc;
  u16 (*lB)[128 * 32] = (u16(*)[128 * 32])(smemc + 32768);
  const int tid = threadIdx.x;
  const int lane = tid & 63;
  const int wid = tid >> 6;

  const int nn = N >> 7;
  const int wgid = (bid & 7) * (nwg >> 3) + (bid >> 3);
  const int tile_m = (wgid / nn) * 256;
  const int tile_n = (wgid % nn) * 128;
  const int wm = wid >> 1, wn = wid & 1;

  const int ldr = lane >> 2;
  const int lko = (lane & 3) * 8;
  const int l15 = lane & 15;
  const int g4 = lane >> 4;

  const size_t aBase = (size_t)tile_m * K;
  const size_t bBase = (size_t)tile_n * K;

  auto stage = [&](int buf, int k0) {
#pragma unroll
    for (int q = 0; q < 2; ++q) {
      int chk = wid * 2 + q;
      int row = chk * 16 + ldr;
      GLD16(A + aBase + (size_t)row * K + k0 + lko, &lA[buf][chk * 512]);
    }
    int row = wid * 16 + ldr;
    GLD16(B + bBase + (size_t)row * K + k0 + lko, &lB[buf][wid * 512]);
  };

  f32x4 acc[4][4];
#pragma unroll
  for (int i = 0; i < 4; ++i)
#pragma unroll
    for (int j = 0; j < 4; ++j) acc[i][j] = (f32x4)0.f;

  stage(0, 0);
  __syncthreads();

  const int NIT = K >> 5;
  for (int it = 0; it < NIT; ++it) {
    const int cur = it & 1;
    if (it + 1 < NIT) stage(cur ^ 1, (it + 1) * 32);
    short8 af[4], bf[4];
#pragma unroll
    for (int i = 0; i < 4; ++i)
      af[i] = *(const short8*)&lA[cur][(wm * 64 + i * 16 + l15) * 32 + g4 * 8];
#pragma unroll
    for (int j = 0; j < 4; ++j)
      bf[j] = *(const short8*)&lB[cur][(wn * 64 + j * 16 + l15) * 32 + g4 * 8];
#pragma unroll
    for (int i = 0; i < 4; ++i)
#pragma unroll
      for (int j = 0; j < 4; ++j)
        acc[i][j] = __builtin_amdgcn_mfma_f32_16x16x32_bf16(af[i], bf[j], acc[i][j], 0, 0, 0);
    __syncthreads();
  }

#pragma unroll
  for (int i = 0; i < 4; ++i) {
    int row0 = tile_m + wm * 64 + i * 16 + (g4 << 2);
#pragma unroll
    for (int j = 0; j < 4; ++j) {
      int col = tile_n + wn * 64 + j * 16 + l15;
      float bv = bias[col];
#pragma unroll
      for (int e = 0; e < 4; ++e)
        C[(size_t)(row0 + e) * (size_t)N + col] = acc[i][j][e] + bv;
    }
  }
}

// ---------------------------------------------------------------------------
// CLUSTERED PERSISTENT LSTM body (r15/r16-proven skeleton). hs_out (decoder)
// is T-MAJOR ([t*64+b][1024]) written with PLAIN packed-u32 stores —
// consumed only by the NEXT kernel (kernel-boundary coherence, the r16-
// proven mechanism). Atomic stores here cost ~2us/step at the coherence
// point (the r20 regression); only the intra-kernel h exchange needs them.
DEVINL void lstm_body(char* smemc, const u16* __restrict__ Whh,
                      const float* __restrict__ Xp, u16* __restrict__ hbuf,
                      u16* __restrict__ hs_out, float* __restrict__ hT_out,
                      u32* arrive, int wgi) {
  char* smemA = smemc;
  float (*lg)[16][16] = (float(*)[16][16])(smemc + 32768);
  const int tid = threadIdx.x;      // 0..511
  const int lane = tid & 63;
  const int v = tid >> 6;           // wave 0..7
  const int gate = v >> 1;
  const int ch = v & 1;             // col-half of the WG's 32 cols
  const int c = wgi >> 5;           // cluster 0..3 (batch rows c*16..+16)
  const int j = wgi & 31;           // WG in cluster (cols j*32..+32)
  const int b0 = c * 16, col0 = j * 32;
  const int l15 = lane & 15, g4 = lane >> 4;

  // Whh fragments: loaded ONCE, live across all 64 steps (128 VGPRs)
  short8 breg[32];
  {
    const u16* Brow = Whh + (size_t)(gate * 1024 + col0 + ch * 16 + l15) * 1024
                          + g4 * 8;
#pragma unroll
    for (int kk = 0; kk < 32; ++kk)
      breg[kk] = *(const short8*)(Brow + kk * 32);
  }

  // cell mapping: 512 threads = 16 rows x 32 cols
  const int crow = tid >> 5, colw = tid & 31;
  const int bg = b0 + crow, cgl = col0 + colw;
  const int ch2 = colw >> 4, cw = colw & 15;
  float creg = 0.f;

  // prologue: Xp prefetch for t=0
  float xg0, xg1, xg2, xg3;
  {
    size_t xrow = (size_t)bg * 4096 + cgl;
    xg0 = __builtin_nontemporal_load(&Xp[xrow]);
    xg1 = __builtin_nontemporal_load(&Xp[xrow + 1024]);
    xg2 = __builtin_nontemporal_load(&Xp[xrow + 2048]);
    xg3 = __builtin_nontemporal_load(&Xp[xrow + 3072]);
  }

  for (int t = 0; t < 64; ++t) {
    const char* rbase = (const char*)(hbuf + (size_t)(t & 1) * 65536)
                      + (size_t)b0 * 2048;
    u32* wb32 = (u32*)(hbuf + (size_t)((t + 1) & 1) * 65536);

    // ---- stage h slab (16 rows x 1024 cols) -> swizzled LDS, atomic loads
#pragma unroll
    for (int q = 0; q < 4; ++q) {
      int g = q * 512 + tid;              // 16B chunk id 0..2047
      int row = g >> 7;                   // 0..15
      int cb = (g & 127) * 16;            // byte col in row
      const u64* src = (const u64*)(rbase + (size_t)row * 2048 + cb);
      u64 lo = __hip_atomic_load(src,     __ATOMIC_RELAXED, __HIP_MEMORY_SCOPE_AGENT);
      u64 hi = __hip_atomic_load(src + 1, __ATOMIC_RELAXED, __HIP_MEMORY_SCOPE_AGENT);
      u64* d = (u64*)(smemA + row * 2048 + (cb ^ ((row & 7) << 4)));
      d[0] = lo; d[1] = hi;
    }
    __syncthreads();

    // ---- 32 MFMAs/wave (4 chains), A from swizzled LDS, B from regs
    f32x4 a4[4] = {(f32x4)0.f, (f32x4)0.f, (f32x4)0.f, (f32x4)0.f};
#pragma unroll
    for (int kk = 0; kk < 32; ++kk) {
      int cb2 = kk * 64 + g4 * 16;
      const short8 a = *(const short8*)(smemA + l15 * 2048 + (cb2 ^ ((l15 & 7) << 4)));
      a4[kk & 3] = __builtin_amdgcn_mfma_f32_16x16x32_bf16(a, breg[kk], a4[kk & 3], 0, 0, 0);
    }
    f32x4 asum = a4[0] + a4[1] + a4[2] + a4[3];
    {
      int m = g4 * 4;
#pragma unroll
      for (int e = 0; e < 4; ++e) lg[v][m + e][l15] = asum[e];
    }
    __syncthreads();

    // ---- cell update: 1 cell per thread (uses prefetched xg)
    {
      float gi = lg[0 + ch2][crow][cw] + xg0;
      float gf = lg[2 + ch2][crow][cw] + xg1;
      float gg = lg[4 + ch2][crow][cw] + xg2;
      float go = lg[6 + ch2][crow][cw] + xg3;
      float si = 1.f / (1.f + __expf(-gi));
      float sf = 1.f / (1.f + __expf(-gf));
      float so = 1.f / (1.f + __expf(-go));
      float tg = tanhf(gg);
      float cn = sf * creg + si * tg;
      float hn = so * tanhf(cn);
      creg = cn;
      u16 h16 = f2bf(hn);
      u32 mine = h16;
      u32 other = (u32)__shfl_xor((int)mine, 1);
      if (!(colw & 1)) {
        u32 pk = mine | (other << 16);
        __hip_atomic_store(wb32 + (((size_t)bg * 1024 + cgl) >> 1), pk,
                           __ATOMIC_RELAXED, __HIP_MEMORY_SCOPE_AGENT);
        if (hs_out)   // t-major, PLAIN store (cross-kernel consumption only)
          ((u32*)hs_out)[(((size_t)t * 64 + bg) * 1024 + cgl) >> 1] = pk;
      }
      if (hT_out && t == 63) hT_out[bg * 1024 + cgl] = hn;   // cross-kernel
    }

    // ---- prefetch next-step Xp, then flat fence-free cluster barrier
    if (t != 63) {
      {
        size_t xrow = (size_t)((t + 1) * 64 + bg) * 4096 + cgl;
        xg0 = __builtin_nontemporal_load(&Xp[xrow]);
        xg1 = __builtin_nontemporal_load(&Xp[xrow + 1024]);
        xg2 = __builtin_nontemporal_load(&Xp[xrow + 2048]);
        xg3 = __builtin_nontemporal_load(&Xp[xrow + 3072]);
      }
      u32 want = (u32)(t + 1);
      asm volatile("s_waitcnt vmcnt(0)" ::: "memory");   // drains h stores + Xp
      __syncthreads();
      if (tid == 0)
        __hip_atomic_store(&arrive[wgi], want, __ATOMIC_RELAXED,
                           __HIP_MEMORY_SCOPE_AGENT);
      if (tid < 32) {
        int guard = 0;
        while (__hip_atomic_load(&arrive[c * 32 + tid], __ATOMIC_RELAXED,
                                 __HIP_MEMORY_SCOPE_AGENT) < want) {
          __builtin_amdgcn_s_sleep(2);
          if (++guard > (1 << 20)) break;   // safety valve
        }
      }
      __syncthreads();
    }
  }
}

// ---------------------------------------------------------------------------
// Standalone LSTM wrapper (encoder fallback + decoder).
__global__ __launch_bounds__(512, 1) void lstm_cluster(
    const u16* __restrict__ Whh, const float* __restrict__ Xp,
    u16* __restrict__ hbuf, u16* __restrict__ hs_out,
    float* __restrict__ hT_out, u32* arrive) {
  __shared__ __align__(16) char smem[40960];
  lstm_body(smem, Whh, Xp, hbuf, hs_out, hT_out, arrive, blockIdx.x);
}

__global__ __launch_bounds__(512) void gemm_bt0(
    const u16* __restrict__ A, const u16* __restrict__ B,
    float* __restrict__ C, const float* __restrict__ bias, int N, int K) {
  __shared__ __align__(16) char smem[49152];
  gemm0_body(smem, blockIdx.x, gridDim.x, A, B, C, bias, N, K);
}

// Fused encoder: blocks 0..127 = encoder LSTM (co-resident); 128..639 =
// decoder-Xp GEMM; 640..1151 = W_out fp32->bf16 conversion (grid-stride).
__global__ __launch_bounds__(512, 1) void enc_fused(
    const u16* __restrict__ whhN, const float* __restrict__ XpE,
    u16* __restrict__ hbuf, float* __restrict__ hT_out, u32* arrive,
    const u16* __restrict__ Xd, const u16* __restrict__ wihD,
    float* __restrict__ XpD, const float* __restrict__ biasD,
    const float* __restrict__ Wout, u16* __restrict__ wout) {
  __shared__ __align__(16) char smem[49152];
  if (blockIdx.x < 128) {
    lstm_body(smem, whhN, XpE, hbuf, nullptr, hT_out, arrive, blockIdx.x);
  } else if (blockIdx.x < 640) {
    gemm0_body(smem, blockIdx.x - 128, 512, Xd, wihD, XpD, biasD, 4096, 1024);
  } else {
    int tid0 = (blockIdx.x - 640) * 512 + threadIdx.x;
    for (int i = tid0; i < 8192000; i += 512 * 512) {
      float4 v = ((const float4*)Wout)[i];
      ushort4 o;
      o.x = f2bf(v.x); o.y = f2bf(v.y); o.z = f2bf(v.z); o.w = f2bf(v.w);
      ((ushort4*)wout)[i] = o;
    }
  }
}

// ---------------------------------------------------------------------------
// Logits GEMM (standalone, serial after decoder LSTM): A = hsd T-MAJOR
// [t*64+b][1024], per-XCD n-partition, 2-phase dbuf, REMAP NT stores
// out[b*64+t][col].
__global__ __launch_bounds__(512) void gemm_bt1(
    const u16* __restrict__ hsd, const u16* __restrict__ wout,
    float* __restrict__ out, const float* __restrict__ b_out) {
  __shared__ u16 lA[2][256 * 32];
  __shared__ u16 lB[2][128 * 32];
  const int tid = threadIdx.x;
  const int lane = tid & 63;
  const int wid = tid >> 6;

  const int i = blockIdx.x;        // 0..4095
  const int x = i & 7;             // XCD id
  const int k = i >> 3;
  const int mg = k >> 6;
  const int r  = k & 63;
  const int kn = r >> 1;
  const int mi = r & 1;
  const int tn = kn * 8 + x;
  if (tn >= 250) return;           // dummy (whole WG exits)
  const int tile_m = (mg * 2 + mi) * 256;
  const int tile_n = tn * 128;
  const int wm = wid >> 1, wn = wid & 1;
  const int N = 32000, K = 1024;

  const int ldr = lane >> 2;
  const int lko = (lane & 3) * 8;
  const int l15 = lane & 15;
  const int g4 = lane >> 4;

  const size_t aBase = (size_t)tile_m * K;
  const size_t bBase = (size_t)tile_n * K;

  auto stg = [&](int buf, int k0) {
#pragma unroll
    for (int q = 0; q < 2; ++q) {
      int chk = wid * 2 + q;
      int row = chk * 16 + ldr;
      GLD16(hsd + aBase + (size_t)row * K + k0 + lko, &lA[buf][chk * 512]);
    }
    int row = wid * 16 + ldr;
    GLD16(wout + bBase + (size_t)row * K + k0 + lko, &lB[buf][wid * 512]);
  };

  f32x4 acc[4][4];
#pragma unroll
  for (int i2 = 0; i2 < 4; ++i2)
#pragma unroll
    for (int j2 = 0; j2 < 4; ++j2) acc[i2][j2] = (f32x4)0.f;

  stg(0, 0);
  __syncthreads();

  const int NIT = K >> 5;
  for (int it = 0; it < NIT; ++it) {
    const int cur = it & 1;
    if (it + 1 < NIT) stg(cur ^ 1, (it + 1) * 32);
    short8 af[4], bf[4];
#pragma unroll
    for (int i2 = 0; i2 < 4; ++i2)
      af[i2] = *(const short8*)&lA[cur][(wm * 64 + i2 * 16 + l15) * 32 + g4 * 8];
#pragma unroll
    for (int j2 = 0; j2 < 4; ++j2)
      bf[j2] = *(const short8*)&lB[cur][(wn * 64 + j2 * 16 + l15) * 32 + g4 * 8];
#pragma unroll
    for (int i2 = 0; i2 < 4; ++i2)
#pragma unroll
      for (int j2 = 0; j2 < 4; ++j2)
        acc[i2][j2] = __builtin_amdgcn_mfma_f32_16x16x32_bf16(af[i2], bf[j2], acc[i2][j2], 0, 0, 0);
    __syncthreads();
  }

#pragma unroll
  for (int i2 = 0; i2 < 4; ++i2) {
    int row0 = tile_m + wm * 64 + i2 * 16 + (g4 << 2);
#pragma unroll
    for (int j2 = 0; j2 < 4; ++j2) {
      int col = tile_n + wn * 64 + j2 * 16 + l15;
      float bv = b_out[col];
#pragma unroll
      for (int e = 0; e < 4; ++e) {
        int rr = row0 + e;                       // t-major row = t*64+b
        size_t o = (size_t)((rr & 63) * 64 + (rr >> 6)) * (size_t)N + col;
        __builtin_nontemporal_store(acc[i2][j2][e] + bv, &out[o]);
      }
    }
  }
}

// ---------------------------------------------------------------------------
// mean/logvar/latent + hd0 = [latent|cond_e] @ W_st^T + b_st -> bf16 h0.
__global__ __launch_bounds__(256) void latent_hd0_kernel(
    const float* hT, const float* Wm, const float* bm,
    const float* Wl, const float* bl, const float* Wst, const float* bst,
    const float* eps, const float* ce, u16* hb0) {
  __shared__ float red[64][4];
  __shared__ float ml[64];
  __shared__ float lat[40];
  int b = blockIdx.x;
  int tid = threadIdx.x;
  int o = tid >> 2, p = tid & 3;
  const float* w = (o < 32) ? (Wm + (size_t)o * 1024) : (Wl + (size_t)(o - 32) * 1024);
  const float* h = hT + (size_t)b * 1024;
  float s = 0.f;
  for (int k = p * 256; k < p * 256 + 256; ++k) s += h[k] * w[k];
  red[o][p] = s;
  __syncthreads();
  if (tid < 64) {
    float v = red[tid][0] + red[tid][1] + red[tid][2] + red[tid][3];
    v += (tid < 32) ? bm[tid] : bl[tid - 32];
    ml[tid] = v;
  }
  __syncthreads();
  if (tid < 32) lat[tid] = eps[b * 32 + tid] * __expf(0.5f * ml[32 + tid]) + ml[tid];
  if (tid >= 32 && tid < 40) lat[tid] = ce[b * 8 + (tid - 32)];
  __syncthreads();
  for (int hc = tid; hc < 1024; hc += 256) {
    float s2 = bst[hc];
    const float* wr = Wst + (size_t)hc * 40;
#pragma unroll
    for (int j = 0; j < 40; ++j) s2 += lat[j] * wr[j];
    hb0[b * 1024 + hc] = f2bf(s2);
  }
}

// ---------------------------------------------------------------------------
extern "C" void kernel_launch(void* const* d_in, const int* in_sizes, int n_in,
                              void* d_out, int out_size, void* d_ws, size_t ws_size,
                              hipStream_t stream) {
  const int*   input_word = (const int*)d_in[0];
  const int*   cond       = (const int*)d_in[1];
  const float* emb_N      = (const float*)d_in[2];
  const float* Wih_N      = (const float*)d_in[3];
  const float* Whh_N      = (const float*)d_in[4];
  const float* bih_N      = (const float*)d_in[5];
  const float* bhh_N      = (const float*)d_in[6];
  const float* emb_D      = (const float*)d_in[7];
  const float* Wih_D      = (const float*)d_in[8];
  const float* Whh_D      = (const float*)d_in[9];
  const float* bih_D      = (const float*)d_in[10];
  const float* bhh_D      = (const float*)d_in[11];
  const float* emb_cond   = (const float*)d_in[12];
  const float* W_mean     = (const float*)d_in[13];
  const float* b_mean     = (const float*)d_in[14];
  const float* W_logvar   = (const float*)d_in[15];
  const float* b_logvar   = (const float*)d_in[16];
  const float* W_st       = (const float*)d_in[17];
  const float* b_st       = (const float*)d_in[18];
  const float* W_out      = (const float*)d_in[19];
  const float* b_out      = (const float*)d_in[20];
  const float* eps        = (const float*)d_in[21];
  float* out = (float*)d_out;

  char* ws = (char*)d_ws;
  size_t off = 0;
  auto alloc = [&](size_t b) { size_t p = off; off += (b + 255) & ~(size_t)255; return p; };
  u16*   wihN = (u16*)(ws + alloc(4096ull * 1024 * 2));
  u16*   whhN = (u16*)(ws + alloc(4096ull * 1024 * 2));
  u16*   wihD = (u16*)(ws + alloc(4096ull * 1024 * 2));
  u16*   whhD = (u16*)(ws + alloc(4096ull * 1024 * 2));
  u16*   wout = (u16*)(ws + alloc(32000ull * 1024 * 2));
  u16*   Xe   = (u16*)(ws + alloc(4096ull * 1024 * 2));
  u16*   Xd   = (u16*)(ws + alloc(4096ull * 1024 * 2));
  float* Xp   = (float*)(ws + alloc(4096ull * 4096 * 4));   // enc (and dec fallback)
  u16*   hsd  = (u16*)(ws + alloc(4096ull * 1024 * 2));     // T-MAJOR [t*64+b][1024]
  u16*   hb   = (u16*)(ws + alloc(2ull * 64 * 1024 * 2));   // bf16 h dbuf
  float* hf   = (float*)(ws + alloc(64ull * 1024 * 4));     // fp32 h_T (encoder)
  float* biasN = (float*)(ws + alloc(4096 * 4));
  float* biasD = (float*)(ws + alloc(4096 * 4));
  float* ce    = (float*)(ws + alloc(64 * 8 * 4));
  u32*   bar   = (u32*)(ws + alloc(4096));
  // bar: enc arrive [0..127], dec arrive [256..383]
  size_t base_off = off;
  float* XpD2 = (float*)(ws + alloc(4096ull * 4096 * 4));   // dec Xp (fused path)
  if (base_off > ws_size) return;
  const bool fused = (off <= ws_size);
  float* XpD = fused ? XpD2 : Xp;

  conv4<<<16384, 256, 0, stream>>>(Wih_N, wihN, Whh_N, whhN,
                                   Wih_D, wihD, Whh_D, whhD);
  prep_small<<<22, 256, 0, stream>>>(cond, emb_cond, bih_N, bhh_N, bih_D, bhh_D,
                                     ce, biasN, biasD, bar);
  gather_kernel<<<4096, 256, 0, stream>>>(emb_N, input_word, Xe, 0);
  gather_kernel<<<4096, 256, 0, stream>>>(emb_D, input_word, Xd, 1);
  init_enc<<<256, 256, 0, stream>>>(ce, hb);

  // encoder Xp
  gemm_bt0<<<512, 512, 0, stream>>>(Xe, wihN, Xp, biasN, 4096, 1024);
  if (fused) {
    // encoder LSTM + decoder-Xp GEMM + W_out conversion, one launch
    enc_fused<<<1152, 512, 0, stream>>>(whhN, Xp, hb, hf, bar + 0,
                                        Xd, wihD, XpD, biasD, W_out, wout);
  } else {
    conv_wout<<<32000, 256, 0, stream>>>(W_out, wout);
    lstm_cluster<<<128, 512, 0, stream>>>(whhN, Xp, hb, nullptr, hf, bar + 0);
  }
  // latent + decoder h0
  latent_hd0_kernel<<<64, 256, 0, stream>>>(hf, W_mean, b_mean, W_logvar, b_logvar,
                                            W_st, b_st, eps, ce, hb);
  if (!fused)
    gemm_bt0<<<512, 512, 0, stream>>>(Xd, wihD, XpD, biasD, 4096, 1024);
  // decoder LSTM (serial) -> t-major hsd (plain stores)
  lstm_cluster<<<128, 512, 0, stream>>>(whhD, XpD, hb, hsd, nullptr, bar + 256);
  // logits GEMM (serial): out[b*64+t] = hsd[t*64+b] @ W_out^T + b_out
  gemm_bt1<<<4096, 512, 0, stream>>>(hsd, wout, out, b_out);
}

// Round 22
// 940.552 us; speedup vs baseline: 1.1032x; 1.0948x over previous
//
#include <hip/hip_runtime.h>
#include <hip/hip_bf16.h>

typedef unsigned short u16;
typedef unsigned int   u32;
typedef unsigned long long u64;
typedef __attribute__((ext_vector_type(8))) short short8;   // 8 x bf16 (4 VGPRs)
typedef __attribute__((ext_vector_type(4))) float f32x4;

#define DEVINL static __device__ __forceinline__

// round-to-nearest-even f32 -> bf16
DEVINL u16 f2bf(float x) {
  u32 u = __float_as_uint(x);
  u32 r = (u + 0x7fffu + ((u >> 16) & 1u)) >> 16;
  return (u16)r;
}

// async global->LDS, 16B per lane. LDS dest = uniform base + lane*16.
#define GLD16(gp, lp) __builtin_amdgcn_global_load_lds(                     \
    (const __attribute__((address_space(1))) u32*)(gp),                     \
    (__attribute__((address_space(3))) u32*)(lp), 16, 0, 0)

// ---------------------------------------------------------------------------
// FRONT-END, one segmented launch: conv4 | prep | gatherE | gatherD | init.
// All segments mutually independent (init reads cond/emb_cond directly).
__global__ __launch_bounds__(256) void front_all(
    const float* __restrict__ s0, u16* __restrict__ d0,
    const float* __restrict__ s1, u16* __restrict__ d1,
    const float* __restrict__ s2, u16* __restrict__ d2,
    const float* __restrict__ s3, u16* __restrict__ d3,
    const int* __restrict__ cond, const float* __restrict__ emb_cond,
    const float* __restrict__ bihN, const float* __restrict__ bhhN,
    const float* __restrict__ bihD, const float* __restrict__ bhhD,
    float* __restrict__ ce, float* __restrict__ biasN, float* __restrict__ biasD,
    u32* __restrict__ bar,
    const float* __restrict__ embN, const float* __restrict__ embD,
    const int* __restrict__ words, u16* __restrict__ Xe, u16* __restrict__ Xd,
    u16* __restrict__ hb0) {
  int blk = blockIdx.x;
  if (blk < 16384) {                       // ---- weight conversion (4x 4Kx1K)
    int p = blk >> 12, local = blk & 4095;
    const float* s = (p == 0) ? s0 : (p == 1) ? s1 : (p == 2) ? s2 : s3;
    u16*         d = (p == 0) ? d0 : (p == 1) ? d1 : (p == 2) ? d2 : d3;
    int i = local * 256 + threadIdx.x;
    float4 v = ((const float4*)s)[i];
    ushort4 o;
    o.x = f2bf(v.x); o.y = f2bf(v.y); o.z = f2bf(v.z); o.w = f2bf(v.w);
    ((ushort4*)d)[i] = o;
  } else if (blk < 16406) {                // ---- prep (ce, biases, barriers)
    int tid = (blk - 16384) * 256 + threadIdx.x;
    if (tid < 512) {
      int b = tid >> 3, j = tid & 7;
      ce[tid] = emb_cond[cond[b] * 8 + j];
    }
    int i = tid - 512;
    if (i >= 0 && i < 4096) {
      biasN[i] = bihN[i] + bhhN[i];
      biasD[i] = bihD[i] + bhhD[i];
    }
    int k = tid - 4608;
    if (k >= 0 && k < 1024) bar[k] = 0;
  } else if (blk < 24598) {                // ---- embedding gathers
    int dec = (blk >= 20502);
    int r = blk - (dec ? 20502 : 16406);   // r = t*64 + b
    int t = r >> 6, b = r & 63;
    int tok = dec ? ((t == 0) ? 0 : words[b * 64 + t - 1]) : words[b * 64 + t];
    const float* emb = dec ? embD : embN;
    u16* X = dec ? Xd : Xe;
    float4 v = ((const float4*)(emb + (size_t)tok * 1024))[threadIdx.x];
    ushort4 o;
    o.x = f2bf(v.x); o.y = f2bf(v.y); o.z = f2bf(v.z); o.w = f2bf(v.w);
    ((ushort4*)(X + (size_t)r * 1024))[threadIdx.x] = o;
  } else {                                 // ---- encoder h0
    int tid = (blk - 24598) * 256 + threadIdx.x;   // 64*1024
    int b = tid >> 10, col = tid & 1023;
    float v = (col >= 1016) ? emb_cond[cond[b] * 8 + (col - 1016)] : 0.f;
    hb0[tid] = f2bf(v);
  }
}

// standalone W_out conversion (fallback path only)
__global__ __launch_bounds__(256) void conv_wout(const float* __restrict__ s,
                                                 u16* __restrict__ d) {
  int i = blockIdx.x * 256 + threadIdx.x;
  float4 v = ((const float4*)s)[i];
  ushort4 o;
  o.x = f2bf(v.x); o.y = f2bf(v.y); o.z = f2bf(v.z); o.w = f2bf(v.w);
  ((ushort4*)d)[i] = o;
}

// ---------------------------------------------------------------------------
// GEMM body, MODE-0 style (n-fast + bijective XCD swizzle), 256x128 tile,
// BK=32, 512 threads = 8 waves (4m x 2n), double-buffered LDS (48KB).
DEVINL void gemm0_body(char* smemc, int bid, int nwg,
                       const u16* __restrict__ A, const u16* __restrict__ B,
                       float* __restrict__ C, const float* __restrict__ bias,
                       int N, int K) {
  u16 (*lA)[256 * 32] = (u16(*)[256 * 32])smemc;
  u16 (*lB)[128 * 32] = (u16(*)[128 * 32])(smemc + 32768);
  const int tid = threadIdx.x;
  const int lane = tid & 63;
  const int wid = tid >> 6;

  const int nn = N >> 7;
  const int wgid = (bid & 7) * (nwg >> 3) + (bid >> 3);
  const int tile_m = (wgid / nn) * 256;
  const int tile_n = (wgid % nn) * 128;
  const int wm = wid >> 1, wn = wid & 1;

  const int ldr = lane >> 2;
  const int lko = (lane & 3) * 8;
  const int l15 = lane & 15;
  const int g4 = lane >> 4;

  const size_t aBase = (size_t)tile_m * K;
  const size_t bBase = (size_t)tile_n * K;

  auto stage = [&](int buf, int k0) {
#pragma unroll
    for (int q = 0; q < 2; ++q) {
      int chk = wid * 2 + q;
      int row = chk * 16 + ldr;
      GLD16(A + aBase + (size_t)row * K + k0 + lko, &lA[buf][chk * 512]);
    }
    int row = wid * 16 + ldr;
    GLD16(B + bBase + (size_t)row * K + k0 + lko, &lB[buf][wid * 512]);
  };

  f32x4 acc[4][4];
#pragma unroll
  for (int i = 0; i < 4; ++i)
#pragma unroll
    for (int j = 0; j < 4; ++j) acc[i][j] = (f32x4)0.f;

  stage(0, 0);
  __syncthreads();

  const int NIT = K >> 5;
  for (int it = 0; it < NIT; ++it) {
    const int cur = it & 1;
    if (it + 1 < NIT) stage(cur ^ 1, (it + 1) * 32);
    short8 af[4], bf[4];
#pragma unroll
    for (int i = 0; i < 4; ++i)
      af[i] = *(const short8*)&lA[cur][(wm * 64 + i * 16 + l15) * 32 + g4 * 8];
#pragma unroll
    for (int j = 0; j < 4; ++j)
      bf[j] = *(const short8*)&lB[cur][(wn * 64 + j * 16 + l15) * 32 + g4 * 8];
#pragma unroll
    for (int i = 0; i < 4; ++i)
#pragma unroll
      for (int j = 0; j < 4; ++j)
        acc[i][j] = __builtin_amdgcn_mfma_f32_16x16x32_bf16(af[i], bf[j], acc[i][j], 0, 0, 0);
    __syncthreads();
  }

#pragma unroll
  for (int i = 0; i < 4; ++i) {
    int row0 = tile_m + wm * 64 + i * 16 + (g4 << 2);
#pragma unroll
    for (int j = 0; j < 4; ++j) {
      int col = tile_n + wn * 64 + j * 16 + l15;
      float bv = bias[col];
#pragma unroll
      for (int e = 0; e < 4; ++e)
        C[(size_t)(row0 + e) * (size_t)N + col] = acc[i][j][e] + bv;
    }
  }
}

// ---------------------------------------------------------------------------
// CLUSTERED PERSISTENT LSTM body (proven skeleton). If prog != null
// (decoder): hs_out is T-MAJOR ([t*64+b][1024]) via packed-u32 agent-atomic
// stores (consumed intra-dispatch); j==0 WG publishes prog[c] per step.
DEVINL void lstm_body(char* smemc, const u16* __restrict__ Whh,
                      const float* __restrict__ Xp, u16* __restrict__ hbuf,
                      u16* __restrict__ hs_out, float* __restrict__ hT_out,
                      u32* arrive, u32* prog, int wgi) {
  __builtin_amdgcn_s_setprio(2);
  char* smemA = smemc;
  float (*lg)[16][16] = (float(*)[16][16])(smemc + 32768);
  const int tid = threadIdx.x;      // 0..511
  const int lane = tid & 63;
  const int v = tid >> 6;           // wave 0..7
  const int gate = v >> 1;
  const int ch = v & 1;             // col-half of the WG's 32 cols
  const int c = wgi >> 5;           // cluster 0..3 (batch rows c*16..+16)
  const int j = wgi & 31;           // WG in cluster (cols j*32..+32)
  const int b0 = c * 16, col0 = j * 32;
  const int l15 = lane & 15, g4 = lane >> 4;

  // Whh fragments: loaded ONCE, live across all 64 steps (128 VGPRs)
  short8 breg[32];
  {
    const u16* Brow = Whh + (size_t)(gate * 1024 + col0 + ch * 16 + l15) * 1024
                          + g4 * 8;
#pragma unroll
    for (int kk = 0; kk < 32; ++kk)
      breg[kk] = *(const short8*)(Brow + kk * 32);
  }

  // cell mapping: 512 threads = 16 rows x 32 cols
  const int crow = tid >> 5, colw = tid & 31;
  const int bg = b0 + crow, cgl = col0 + colw;
  const int ch2 = colw >> 4, cw = colw & 15;
  float creg = 0.f;

  // prologue: Xp prefetch for t=0
  float xg0, xg1, xg2, xg3;
  {
    size_t xrow = (size_t)bg * 4096 + cgl;
    xg0 = __builtin_nontemporal_load(&Xp[xrow]);
    xg1 = __builtin_nontemporal_load(&Xp[xrow + 1024]);
    xg2 = __builtin_nontemporal_load(&Xp[xrow + 2048]);
    xg3 = __builtin_nontemporal_load(&Xp[xrow + 3072]);
  }

  for (int t = 0; t < 64; ++t) {
    const char* rbase = (const char*)(hbuf + (size_t)(t & 1) * 65536)
                      + (size_t)b0 * 2048;
    u32* wb32 = (u32*)(hbuf + (size_t)((t + 1) & 1) * 65536);

    // ---- stage h slab (16 rows x 1024 cols) -> swizzled LDS, atomic loads
#pragma unroll
    for (int q = 0; q < 4; ++q) {
      int g = q * 512 + tid;              // 16B chunk id 0..2047
      int row = g >> 7;                   // 0..15
      int cb = (g & 127) * 16;            // byte col in row
      const u64* src = (const u64*)(rbase + (size_t)row * 2048 + cb);
      u64 lo = __hip_atomic_load(src,     __ATOMIC_RELAXED, __HIP_MEMORY_SCOPE_AGENT);
      u64 hi = __hip_atomic_load(src + 1, __ATOMIC_RELAXED, __HIP_MEMORY_SCOPE_AGENT);
      u64* d = (u64*)(smemA + row * 2048 + (cb ^ ((row & 7) << 4)));
      d[0] = lo; d[1] = hi;
    }
    __syncthreads();

    // ---- 32 MFMAs/wave (4 chains), A from swizzled LDS, B from regs
    f32x4 a4[4] = {(f32x4)0.f, (f32x4)0.f, (f32x4)0.f, (f32x4)0.f};
#pragma unroll
    for (int kk = 0; kk < 32; ++kk) {
      int cb2 = kk * 64 + g4 * 16;
      const short8 a = *(const short8*)(smemA + l15 * 2048 + (cb2 ^ ((l15 & 7) << 4)));
      a4[kk & 3] = __builtin_amdgcn_mfma_f32_16x16x32_bf16(a, breg[kk], a4[kk & 3], 0, 0, 0);
    }
    f32x4 asum = a4[0] + a4[1] + a4[2] + a4[3];
    {
      int m = g4 * 4;
#pragma unroll
      for (int e = 0; e < 4; ++e) lg[v][m + e][l15] = asum[e];
    }
    __syncthreads();

    // ---- cell update: 1 cell per thread (uses prefetched xg)
    {
      float gi = lg[0 + ch2][crow][cw] + xg0;
      float gf = lg[2 + ch2][crow][cw] + xg1;
      float gg = lg[4 + ch2][crow][cw] + xg2;
      float go = lg[6 + ch2][crow][cw] + xg3;
      float si = 1.f / (1.f + __expf(-gi));
      float sf = 1.f / (1.f + __expf(-gf));
      float so = 1.f / (1.f + __expf(-go));
      float tg = tanhf(gg);
      float cn = sf * creg + si * tg;
      float hn = so * tanhf(cn);
      creg = cn;
      u16 h16 = f2bf(hn);
      u32 mine = h16;
      u32 other = (u32)__shfl_xor((int)mine, 1);
      if (!(colw & 1)) {
        u32 pk = mine | (other << 16);
        __hip_atomic_store(wb32 + (((size_t)bg * 1024 + cgl) >> 1), pk,
                           __ATOMIC_RELAXED, __HIP_MEMORY_SCOPE_AGENT);
        if (hs_out)   // t-major, write-through (consumed intra-dispatch)
          __hip_atomic_store((u32*)hs_out + ((((size_t)t * 64 + bg) * 1024 + cgl) >> 1),
                             pk, __ATOMIC_RELAXED, __HIP_MEMORY_SCOPE_AGENT);
      }
      if (hT_out && t == 63) hT_out[bg * 1024 + cgl] = hn;   // cross-kernel
    }

    // ---- prefetch next-step Xp, then flat fence-free cluster barrier
    if (t != 63) {
      {
        size_t xrow = (size_t)((t + 1) * 64 + bg) * 4096 + cgl;
        xg0 = __builtin_nontemporal_load(&Xp[xrow]);
        xg1 = __builtin_nontemporal_load(&Xp[xrow + 1024]);
        xg2 = __builtin_nontemporal_load(&Xp[xrow + 2048]);
        xg3 = __builtin_nontemporal_load(&Xp[xrow + 3072]);
      }
      u32 want = (u32)(t + 1);
      asm volatile("s_waitcnt vmcnt(0)" ::: "memory");   // drains h/hsd stores + Xp
      __syncthreads();
      if (tid == 0)
        __hip_atomic_store(&arrive[wgi], want, __ATOMIC_RELAXED,
                           __HIP_MEMORY_SCOPE_AGENT);
      if (tid < 32) {
        int guard = 0;
        while (__hip_atomic_load(&arrive[c * 32 + tid], __ATOMIC_RELAXED,
                                 __HIP_MEMORY_SCOPE_AGENT) < want) {
          __builtin_amdgcn_s_sleep(2);
          if (++guard > (1 << 20)) break;   // safety valve
        }
      }
      __syncthreads();
      if (prog && j == 0 && tid == 0)
        __hip_atomic_store(&prog[c], want, __ATOMIC_RELAXED,
                           __HIP_MEMORY_SCOPE_AGENT);
    }
  }

  // ---- final drain + publish prog = 64 (decoder only)
  if (prog) {
    asm volatile("s_waitcnt vmcnt(0)" ::: "memory");
    __syncthreads();
    if (tid == 0)
      __hip_atomic_store(&arrive[wgi], 64u, __ATOMIC_RELAXED,
                         __HIP_MEMORY_SCOPE_AGENT);
    if (j == 0) {
      if (tid < 32) {
        int guard = 0;
        while (__hip_atomic_load(&arrive[c * 32 + tid], __ATOMIC_RELAXED,
                                 __HIP_MEMORY_SCOPE_AGENT) < 64u) {
          __builtin_amdgcn_s_sleep(2);
          if (++guard > (1 << 20)) break;
        }
      }
      __syncthreads();
      if (tid == 0)
        __hip_atomic_store(&prog[c], 64u, __ATOMIC_RELAXED,
                           __HIP_MEMORY_SCOPE_AGENT);
    }
  }
  __builtin_amdgcn_s_setprio(0);
}

// ---------------------------------------------------------------------------
// Standalone LSTM wrapper (encoder fallback path).
__global__ __launch_bounds__(512, 1) void lstm_cluster(
    const u16* __restrict__ Whh, const float* __restrict__ Xp,
    u16* __restrict__ hbuf, float* __restrict__ hT_out, u32* arrive) {
  __shared__ __align__(16) char smem[40960];
  lstm_body(smem, Whh, Xp, hbuf, nullptr, hT_out, arrive, nullptr, blockIdx.x);
}

__global__ __launch_bounds__(512) void gemm_bt0(
    const u16* __restrict__ A, const u16* __restrict__ B,
    float* __restrict__ C, const float* __restrict__ bias, int N, int K) {
  __shared__ __align__(16) char smem[49152];
  gemm0_body(smem, blockIdx.x, gridDim.x, A, B, C, bias, N, K);
}

// Fused encoder: blocks 0..127 = encoder LSTM (co-resident); 128..639 =
// decoder-Xp GEMM; 640..1151 = W_out fp32->bf16 conversion (grid-stride).
__global__ __launch_bounds__(512, 1) void enc_fused(
    const u16* __restrict__ whhN, const float* __restrict__ XpE,
    u16* __restrict__ hbuf, float* __restrict__ hT_out, u32* arrive,
    const u16* __restrict__ Xd, const u16* __restrict__ wihD,
    float* __restrict__ XpD, const float* __restrict__ biasD,
    const float* __restrict__ Wout, u16* __restrict__ wout) {
  __shared__ __align__(16) char smem[49152];
  if (blockIdx.x < 128) {
    lstm_body(smem, whhN, XpE, hbuf, nullptr, hT_out, arrive, nullptr, blockIdx.x);
  } else if (blockIdx.x < 640) {
    gemm0_body(smem, blockIdx.x - 128, 512, Xd, wihD, XpD, biasD, 4096, 1024);
  } else {
    int tid0 = (blockIdx.x - 640) * 512 + threadIdx.x;
    for (int i = tid0; i < 8192000; i += 512 * 512) {
      float4 v = ((const float4*)Wout)[i];
      ushort4 o;
      o.x = f2bf(v.x); o.y = f2bf(v.y); o.z = f2bf(v.z); o.w = f2bf(v.w);
      ((ushort4*)wout)[i] = o;
    }
  }
}

// ---------------------------------------------------------------------------
// Fused decoder: blocks 0..127 = decoder LSTM (prio 2, t-major hsd + prog);
// blocks 128..4223 = logits GEMM, per-XCD n-partition, gated on prog, with
// 3-BUFFER COUNTED-VMCNT pipeline (T4): stage(k+1) -> vmcnt(3) -> s_barrier
// -> compute(k). Loads span the barrier instead of a forced vmcnt(0) drain.
// Race-free: between consecutive barriers a wave does {compute(k-1),
// stage(k+1)} -> buffers (k-1)%3 != (k+1)%3; in-order vmem retirement makes
// vmcnt(3) certify stage(k) landed. REMAP NT store to out[b*64+t].
__global__ __launch_bounds__(512, 1) void dec_fused(
    const u16* __restrict__ whhD, const float* __restrict__ XpD,
    u16* __restrict__ hbuf, u16* __restrict__ hsd, u32* arrive, u32* prog,
    const u16* __restrict__ wout, float* __restrict__ out,
    const float* __restrict__ b_out) {
  __shared__ __align__(16) char smem[73728];   // 3x16KB A + 3x8KB B
  if (blockIdx.x < 128) {
    lstm_body(smem, whhD, XpD, hbuf, hsd, nullptr, arrive, prog, blockIdx.x);
    return;
  }
  // ---- logits GEMM part
  u16 (*lA)[256 * 32] = (u16(*)[256 * 32])smem;            // 3 bufs
  u16 (*lB)[128 * 32] = (u16(*)[128 * 32])(smem + 49152);  // 3 bufs
  const int tid = threadIdx.x;
  const int lane = tid & 63;
  const int wid = tid >> 6;

  const int i = blockIdx.x - 128;  // 0..4095
  const int x = i & 7;             // XCD id
  const int k = i >> 3;
  const int mg = k >> 6;
  const int r  = k & 63;
  const int kn = r >> 1;
  const int mi = r & 1;
  const int tn = kn * 8 + x;
  if (tn >= 250) return;           // dummy (whole WG exits)
  const int mt = mg * 2 + mi;      // m-tile = t-chunk [mt*4, mt*4+4)
  const int tile_m = mt * 256;
  const int tile_n = tn * 128;
  const int wm = wid >> 1, wn = wid & 1;
  const int N = 32000, K = 1024;

  // ---- wait until decoder steps 0..mt*4+3 are complete in all clusters
  {
    u32 need = (u32)(mt * 4 + 4);
    if (tid < 4) {
      int guard = 0;
      while (__hip_atomic_load(&prog[tid], __ATOMIC_RELAXED,
                               __HIP_MEMORY_SCOPE_AGENT) < need) {
        __builtin_amdgcn_s_sleep(8);
        if (++guard > (1 << 22)) break;   // safety valve
      }
    }
    __syncthreads();
  }

  const int ldr = lane >> 2;
  const int lko = (lane & 3) * 8;
  const int l15 = lane & 15;
  const int g4 = lane >> 4;

  const size_t aBase = (size_t)tile_m * K;
  const size_t bBase = (size_t)tile_n * K;

  auto stg = [&](int buf, int k0) {
#pragma unroll
    for (int q = 0; q < 2; ++q) {
      int chk = wid * 2 + q;
      int row = chk * 16 + ldr;
      GLD16(hsd + aBase + (size_t)row * K + k0 + lko, &lA[buf][chk * 512]);
    }
    int row = wid * 16 + ldr;
    GLD16(wout + bBase + (size_t)row * K + k0 + lko, &lB[buf][wid * 512]);
  };

  f32x4 acc[4][4];
#pragma unroll
  for (int i2 = 0; i2 < 4; ++i2)
#pragma unroll
    for (int j2 = 0; j2 < 4; ++j2) acc[i2][j2] = (f32x4)0.f;

  stg(0, 0);                           // prologue: tile 0 in flight

  const int NIT = K >> 5;              // 32
  for (int it = 0; it < NIT; ++it) {
    const int cur = it % 3;
    if (it + 1 < NIT) {
      stg((it + 1) % 3, (it + 1) * 32);
      asm volatile("s_waitcnt vmcnt(3)" ::: "memory");  // tile it landed; it+1 flies
    } else {
      asm volatile("s_waitcnt vmcnt(0)" ::: "memory");  // last tile: full drain
    }
    __builtin_amdgcn_s_barrier();
    short8 af[4], bf[4];
#pragma unroll
    for (int i2 = 0; i2 < 4; ++i2)
      af[i2] = *(const short8*)&lA[cur][(wm * 64 + i2 * 16 + l15) * 32 + g4 * 8];
#pragma unroll
    for (int j2 = 0; j2 < 4; ++j2)
      bf[j2] = *(const short8*)&lB[cur][(wn * 64 + j2 * 16 + l15) * 32 + g4 * 8];
#pragma unroll
    for (int i2 = 0; i2 < 4; ++i2)
#pragma unroll
      for (int j2 = 0; j2 < 4; ++j2)
        acc[i2][j2] = __builtin_amdgcn_mfma_f32_16x16x32_bf16(af[i2], bf[j2], acc[i2][j2], 0, 0, 0);
  }

#pragma unroll
  for (int i2 = 0; i2 < 4; ++i2) {
    int row0 = tile_m + wm * 64 + i2 * 16 + (g4 << 2);
#pragma unroll
    for (int j2 = 0; j2 < 4; ++j2) {
      int col = tile_n + wn * 64 + j2 * 16 + l15;
      float bv = b_out[col];
#pragma unroll
      for (int e = 0; e < 4; ++e) {
        int rr = row0 + e;                       // t-major row = t*64+b
        size_t o = (size_t)((rr & 63) * 64 + (rr >> 6)) * (size_t)N + col;
        __builtin_nontemporal_store(acc[i2][j2][e] + bv, &out[o]);
      }
    }
  }
}

// ---------------------------------------------------------------------------
// mean/logvar/latent + hd0 = [latent|cond_e] @ W_st^T + b_st -> bf16 h0.
__global__ __launch_bounds__(256) void latent_hd0_kernel(
    const float* hT, const float* Wm, const float* bm,
    const float* Wl, const float* bl, const float* Wst, const float* bst,
    const float* eps, const float* ce, u16* hb0) {
  __shared__ float red[64][4];
  __shared__ float ml[64];
  __shared__ float lat[40];
  int b = blockIdx.x;
  int tid = threadIdx.x;
  int o = tid >> 2, p = tid & 3;
  const float* w = (o < 32) ? (Wm + (size_t)o * 1024) : (Wl + (size_t)(o - 32) * 1024);
  const float* h = hT + (size_t)b * 1024;
  float s = 0.f;
  for (int k = p * 256; k < p * 256 + 256; ++k) s += h[k] * w[k];
  red[o][p] = s;
  __syncthreads();
  if (tid < 64) {
    float v = red[tid][0] + red[tid][1] + red[tid][2] + red[tid][3];
    v += (tid < 32) ? bm[tid] : bl[tid - 32];
    ml[tid] = v;
  }
  __syncthreads();
  if (tid < 32) lat[tid] = eps[b * 32 + tid] * __expf(0.5f * ml[32 + tid]) + ml[tid];
  if (tid >= 32 && tid < 40) lat[tid] = ce[b * 8 + (tid - 32)];
  __syncthreads();
  for (int hc = tid; hc < 1024; hc += 256) {
    float s2 = bst[hc];
    const float* wr = Wst + (size_t)hc * 40;
#pragma unroll
    for (int j = 0; j < 40; ++j) s2 += lat[j] * wr[j];
    hb0[b * 1024 + hc] = f2bf(s2);
  }
}

// ---------------------------------------------------------------------------
extern "C" void kernel_launch(void* const* d_in, const int* in_sizes, int n_in,
                              void* d_out, int out_size, void* d_ws, size_t ws_size,
                              hipStream_t stream) {
  const int*   input_word = (const int*)d_in[0];
  const int*   cond       = (const int*)d_in[1];
  const float* emb_N      = (const float*)d_in[2];
  const float* Wih_N      = (const float*)d_in[3];
  const float* Whh_N      = (const float*)d_in[4];
  const float* bih_N      = (const float*)d_in[5];
  const float* bhh_N      = (const float*)d_in[6];
  const float* emb_D      = (const float*)d_in[7];
  const float* Wih_D      = (const float*)d_in[8];
  const float* Whh_D      = (const float*)d_in[9];
  const float* bih_D      = (const float*)d_in[10];
  const float* bhh_D      = (const float*)d_in[11];
  const float* emb_cond   = (const float*)d_in[12];
  const float* W_mean     = (const float*)d_in[13];
  const float* b_mean     = (const float*)d_in[14];
  const float* W_logvar   = (const float*)d_in[15];
  const float* b_logvar   = (const float*)d_in[16];
  const float* W_st       = (const float*)d_in[17];
  const float* b_st       = (const float*)d_in[18];
  const float* W_out      = (const float*)d_in[19];
  const float* b_out      = (const float*)d_in[20];
  const float* eps        = (const float*)d_in[21];
  float* out = (float*)d_out;

  char* ws = (char*)d_ws;
  size_t off = 0;
  auto alloc = [&](size_t b) { size_t p = off; off += (b + 255) & ~(size_t)255; return p; };
  u16*   wihN = (u16*)(ws + alloc(4096ull * 1024 * 2));
  u16*   whhN = (u16*)(ws + alloc(4096ull * 1024 * 2));
  u16*   wihD = (u16*)(ws + alloc(4096ull * 1024 * 2));
  u16*   whhD = (u16*)(ws + alloc(4096ull * 1024 * 2));
  u16*   wout = (u16*)(ws + alloc(32000ull * 1024 * 2));
  u16*   Xe   = (u16*)(ws + alloc(4096ull * 1024 * 2));
  u16*   Xd   = (u16*)(ws + alloc(4096ull * 1024 * 2));
  float* Xp   = (float*)(ws + alloc(4096ull * 4096 * 4));   // enc (and dec fallback)
  u16*   hsd  = (u16*)(ws + alloc(4096ull * 1024 * 2));     // T-MAJOR [t*64+b][1024]
  u16*   hb   = (u16*)(ws + alloc(2ull * 64 * 1024 * 2));   // bf16 h dbuf
  float* hf   = (float*)(ws + alloc(64ull * 1024 * 4));     // fp32 h_T (encoder)
  float* biasN = (float*)(ws + alloc(4096 * 4));
  float* biasD = (float*)(ws + alloc(4096 * 4));
  float* ce    = (float*)(ws + alloc(64 * 8 * 4));
  u32*   bar   = (u32*)(ws + alloc(4096));
  // bar: enc arrive [0..127], dec arrive [256..383], dec prog [512..515]
  size_t base_off = off;
  float* XpD2 = (float*)(ws + alloc(4096ull * 4096 * 4));   // dec Xp (fused path)
  if (base_off > ws_size) return;
  const bool fused = (off <= ws_size);
  float* XpD = fused ? XpD2 : Xp;

  // front-end: weights conv + prep + gathers + h0 init, one launch
  front_all<<<24854, 256, 0, stream>>>(Wih_N, wihN, Whh_N, whhN,
                                       Wih_D, wihD, Whh_D, whhD,
                                       cond, emb_cond,
                                       bih_N, bhh_N, bih_D, bhh_D,
                                       ce, biasN, biasD, bar,
                                       emb_N, emb_D, input_word, Xe, Xd, hb);

  // encoder Xp
  gemm_bt0<<<512, 512, 0, stream>>>(Xe, wihN, Xp, biasN, 4096, 1024);
  if (fused) {
    // encoder LSTM + decoder-Xp GEMM + W_out conversion, one launch
    enc_fused<<<1152, 512, 0, stream>>>(whhN, Xp, hb, hf, bar + 0,
                                        Xd, wihD, XpD, biasD, W_out, wout);
  } else {
    conv_wout<<<32000, 256, 0, stream>>>(W_out, wout);
    lstm_cluster<<<128, 512, 0, stream>>>(whhN, Xp, hb, hf, bar + 0);
  }
  // latent + decoder h0
  latent_hd0_kernel<<<64, 256, 0, stream>>>(hf, W_mean, b_mean, W_logvar, b_logvar,
                                            W_st, b_st, eps, ce, hb);
  if (!fused)
    gemm_bt0<<<512, 512, 0, stream>>>(Xd, wihD, XpD, biasD, 4096, 1024);
  // decoder LSTM + logits GEMM fused (producer-consumer on hsd via prog[])
  dec_fused<<<4224, 512, 0, stream>>>(whhD, XpD, hb, hsd, bar + 256, bar + 512,
                                      wout, out, b_out);
}

// Round 23
// 936.646 us; speedup vs baseline: 1.1078x; 1.0042x over previous
//
#include <hip/hip_runtime.h>
#include <hip/hip_bf16.h>

typedef unsigned short u16;
typedef unsigned int   u32;
typedef unsigned long long u64;
typedef __attribute__((ext_vector_type(8))) short short8;   // 8 x bf16 (4 VGPRs)
typedef __attribute__((ext_vector_type(4))) float f32x4;

#define DEVINL static __device__ __forceinline__

// round-to-nearest-even f32 -> bf16
DEVINL u16 f2bf(float x) {
  u32 u = __float_as_uint(x);
  u32 r = (u + 0x7fffu + ((u >> 16) & 1u)) >> 16;
  return (u16)r;
}

// async global->LDS, 16B per lane. LDS dest = uniform base + lane*16.
#define GLD16(gp, lp) __builtin_amdgcn_global_load_lds(                     \
    (const __attribute__((address_space(1))) u32*)(gp),                     \
    (__attribute__((address_space(3))) u32*)(lp), 16, 0, 0)

// ---------------------------------------------------------------------------
// FRONT-END, one segmented launch: conv4 | prep | gatherE | gatherD | init.
__global__ __launch_bounds__(256) void front_all(
    const float* __restrict__ s0, u16* __restrict__ d0,
    const float* __restrict__ s1, u16* __restrict__ d1,
    const float* __restrict__ s2, u16* __restrict__ d2,
    const float* __restrict__ s3, u16* __restrict__ d3,
    const int* __restrict__ cond, const float* __restrict__ emb_cond,
    const float* __restrict__ bihN, const float* __restrict__ bhhN,
    const float* __restrict__ bihD, const float* __restrict__ bhhD,
    float* __restrict__ ce, float* __restrict__ biasN, float* __restrict__ biasD,
    u32* __restrict__ bar,
    const float* __restrict__ embN, const float* __restrict__ embD,
    const int* __restrict__ words, u16* __restrict__ Xe, u16* __restrict__ Xd,
    u16* __restrict__ hb0) {
  int blk = blockIdx.x;
  if (blk < 16384) {                       // ---- weight conversion (4x 4Kx1K)
    int p = blk >> 12, local = blk & 4095;
    const float* s = (p == 0) ? s0 : (p == 1) ? s1 : (p == 2) ? s2 : s3;
    u16*         d = (p == 0) ? d0 : (p == 1) ? d1 : (p == 2) ? d2 : d3;
    int i = local * 256 + threadIdx.x;
    float4 v = ((const float4*)s)[i];
    ushort4 o;
    o.x = f2bf(v.x); o.y = f2bf(v.y); o.z = f2bf(v.z); o.w = f2bf(v.w);
    ((ushort4*)d)[i] = o;
  } else if (blk < 16406) {                // ---- prep (ce, biases, barriers)
    int tid = (blk - 16384) * 256 + threadIdx.x;
    if (tid < 512) {
      int b = tid >> 3, j = tid & 7;
      ce[tid] = emb_cond[cond[b] * 8 + j];
    }
    int i = tid - 512;
    if (i >= 0 && i < 4096) {
      biasN[i] = bihN[i] + bhhN[i];
      biasD[i] = bihD[i] + bhhD[i];
    }
    int k = tid - 4608;
    if (k >= 0 && k < 1024) bar[k] = 0;
  } else if (blk < 24598) {                // ---- embedding gathers
    int dec = (blk >= 20502);
    int r = blk - (dec ? 20502 : 16406);   // r = t*64 + b
    int t = r >> 6, b = r & 63;
    int tok = dec ? ((t == 0) ? 0 : words[b * 64 + t - 1]) : words[b * 64 + t];
    const float* emb = dec ? embD : embN;
    u16* X = dec ? Xd : Xe;
    float4 v = ((const float4*)(emb + (size_t)tok * 1024))[threadIdx.x];
    ushort4 o;
    o.x = f2bf(v.x); o.y = f2bf(v.y); o.z = f2bf(v.z); o.w = f2bf(v.w);
    ((ushort4*)(X + (size_t)r * 1024))[threadIdx.x] = o;
  } else {                                 // ---- encoder h0
    int tid = (blk - 24598) * 256 + threadIdx.x;   // 64*1024
    int b = tid >> 10, col = tid & 1023;
    float v = (col >= 1016) ? emb_cond[cond[b] * 8 + (col - 1016)] : 0.f;
    hb0[tid] = f2bf(v);
  }
}

// standalone W_out conversion (fallback path only)
__global__ __launch_bounds__(256) void conv_wout(const float* __restrict__ s,
                                                 u16* __restrict__ d) {
  int i = blockIdx.x * 256 + threadIdx.x;
  float4 v = ((const float4*)s)[i];
  ushort4 o;
  o.x = f2bf(v.x); o.y = f2bf(v.y); o.z = f2bf(v.z); o.w = f2bf(v.w);
  ((ushort4*)d)[i] = o;
}

// ---------------------------------------------------------------------------
// GEMM body, MODE-0 style (n-fast + bijective XCD swizzle), 256x128 tile,
// BK=32, 512 threads = 8 waves (4m x 2n), double-buffered LDS (48KB).
DEVINL void gemm0_body(char* smemc, int bid, int nwg,
                       const u16* __restrict__ A, const u16* __restrict__ B,
                       float* __restrict__ C, const float* __restrict__ bias,
                       int N, int K) {
  u16 (*lA)[256 * 32] = (u16(*)[256 * 32])smemc;
  u16 (*lB)[128 * 32] = (u16(*)[128 * 32])(smemc + 32768);
  const int tid = threadIdx.x;
  const int lane = tid & 63;
  const int wid = tid >> 6;

  const int nn = N >> 7;
  const int wgid = (bid & 7) * (nwg >> 3) + (bid >> 3);
  const int tile_m = (wgid / nn) * 256;
  const int tile_n = (wgid % nn) * 128;
  const int wm = wid >> 1, wn = wid & 1;

  const int ldr = lane >> 2;
  const int lko = (lane & 3) * 8;
  const int l15 = lane & 15;
  const int g4 = lane >> 4;

  const size_t aBase = (size_t)tile_m * K;
  const size_t bBase = (size_t)tile_n * K;

  auto stage = [&](int buf, int k0) {
#pragma unroll
    for (int q = 0; q < 2; ++q) {
      int chk = wid * 2 + q;
      int row = chk * 16 + ldr;
      GLD16(A + aBase + (size_t)row * K + k0 + lko, &lA[buf][chk * 512]);
    }
    int row = wid * 16 + ldr;
    GLD16(B + bBase + (size_t)row * K + k0 + lko, &lB[buf][wid * 512]);
  };

  f32x4 acc[4][4];
#pragma unroll
  for (int i = 0; i < 4; ++i)
#pragma unroll
    for (int j = 0; j < 4; ++j) acc[i][j] = (f32x4)0.f;

  stage(0, 0);
  __syncthreads();

  const int NIT = K >> 5;
  for (int it = 0; it < NIT; ++it) {
    const int cur = it & 1;
    if (it + 1 < NIT) stage(cur ^ 1, (it + 1) * 32);
    short8 af[4], bf[4];
#pragma unroll
    for (int i = 0; i < 4; ++i)
      af[i] = *(const short8*)&lA[cur][(wm * 64 + i * 16 + l15) * 32 + g4 * 8];
#pragma unroll
    for (int j = 0; j < 4; ++j)
      bf[j] = *(const short8*)&lB[cur][(wn * 64 + j * 16 + l15) * 32 + g4 * 8];
#pragma unroll
    for (int i = 0; i < 4; ++i)
#pragma unroll
      for (int j = 0; j < 4; ++j)
        acc[i][j] = __builtin_amdgcn_mfma_f32_16x16x32_bf16(af[i], bf[j], acc[i][j], 0, 0, 0);
    __syncthreads();
  }

#pragma unroll
  for (int i = 0; i < 4; ++i) {
    int row0 = tile_m + wm * 64 + i * 16 + (g4 << 2);
#pragma unroll
    for (int j = 0; j < 4; ++j) {
      int col = tile_n + wn * 64 + j * 16 + l15;
      float bv = bias[col];
#pragma unroll
      for (int e = 0; e < 4; ++e)
        C[(size_t)(row0 + e) * (size_t)N + col] = acc[i][j][e] + bv;
    }
  }
}

// ---------------------------------------------------------------------------
// XpE PRODUCER: 128 blocks; block p owns n-panel (p&31) and walks m-tiles
// mt = r*4 + (p>>5), r=0..3 — t-chunks 0..3 complete after round one.
// NT stores (write-through) + vmcnt(0) + atomicAdd done[mt] (release).
DEVINL void xpe_producer(char* smemc, int p,
                         const u16* __restrict__ Xe, const u16* __restrict__ W,
                         float* __restrict__ Xp, const float* __restrict__ bias,
                         u32* __restrict__ done) {
  u16 (*lA)[256 * 32] = (u16(*)[256 * 32])smemc;
  u16 (*lB)[128 * 32] = (u16(*)[128 * 32])(smemc + 32768);
  const int tid = threadIdx.x;
  const int lane = tid & 63;
  const int wid = tid >> 6;
  const int n = p & 31, mq = p >> 5;
  const int wm = wid >> 1, wn = wid & 1;
  const int ldr = lane >> 2;
  const int lko = (lane & 3) * 8;
  const int l15 = lane & 15;
  const int g4 = lane >> 4;
  const int N = 4096, K = 1024;
  const int tile_n = n * 128;
  const size_t bBase = (size_t)tile_n * K;

  for (int r2 = 0; r2 < 4; ++r2) {
    const int mt = r2 * 4 + mq;
    const int tile_m = mt * 256;
    const size_t aBase = (size_t)tile_m * K;

    auto stage = [&](int buf, int k0) {
#pragma unroll
      for (int q = 0; q < 2; ++q) {
        int chk = wid * 2 + q;
        int row = chk * 16 + ldr;
        GLD16(Xe + aBase + (size_t)row * K + k0 + lko, &lA[buf][chk * 512]);
      }
      int row = wid * 16 + ldr;
      GLD16(W + bBase + (size_t)row * K + k0 + lko, &lB[buf][wid * 512]);
    };

    f32x4 acc[4][4];
#pragma unroll
    for (int i = 0; i < 4; ++i)
#pragma unroll
      for (int j = 0; j < 4; ++j) acc[i][j] = (f32x4)0.f;

    stage(0, 0);
    __syncthreads();
    const int NIT = K >> 5;
    for (int it = 0; it < NIT; ++it) {
      const int cur = it & 1;
      if (it + 1 < NIT) stage(cur ^ 1, (it + 1) * 32);
      short8 af[4], bf[4];
#pragma unroll
      for (int i = 0; i < 4; ++i)
        af[i] = *(const short8*)&lA[cur][(wm * 64 + i * 16 + l15) * 32 + g4 * 8];
#pragma unroll
      for (int j = 0; j < 4; ++j)
        bf[j] = *(const short8*)&lB[cur][(wn * 64 + j * 16 + l15) * 32 + g4 * 8];
#pragma unroll
      for (int i = 0; i < 4; ++i)
#pragma unroll
        for (int j = 0; j < 4; ++j)
          acc[i][j] = __builtin_amdgcn_mfma_f32_16x16x32_bf16(af[i], bf[j], acc[i][j], 0, 0, 0);
      __syncthreads();
    }

#pragma unroll
    for (int i = 0; i < 4; ++i) {
      int row0 = tile_m + wm * 64 + i * 16 + (g4 << 2);
#pragma unroll
      for (int j = 0; j < 4; ++j) {
        int col = tile_n + wn * 64 + j * 16 + l15;
        float bv = bias[col];
#pragma unroll
        for (int e = 0; e < 4; ++e)
          __builtin_nontemporal_store(acc[i][j][e] + bv,
                                      &Xp[(size_t)(row0 + e) * (size_t)N + col]);
      }
    }
    asm volatile("s_waitcnt vmcnt(0)" ::: "memory");   // NT stores at coh point
    __syncthreads();
    if (tid == 0)
      __hip_atomic_fetch_add(&done[mt], 1u, __ATOMIC_RELEASE,
                             __HIP_MEMORY_SCOPE_AGENT);
    __syncthreads();
  }
}

// ---------------------------------------------------------------------------
// CLUSTERED PERSISTENT LSTM body (proven skeleton). If prog != null
// (decoder): hs_out is T-MAJOR via packed-u32 agent-atomic stores; j==0 WG
// publishes prog[c] per step. If xpdone != null (encoder fused with XpE
// producer): gate each 4-step Xp prefetch window on done[chunk] == 32.
DEVINL void lstm_body(char* smemc, const u16* __restrict__ Whh,
                      const float* __restrict__ Xp, u16* __restrict__ hbuf,
                      u16* __restrict__ hs_out, float* __restrict__ hT_out,
                      u32* arrive, u32* prog, u32* xpdone, int wgi) {
  __builtin_amdgcn_s_setprio(2);
  char* smemA = smemc;
  float (*lg)[16][16] = (float(*)[16][16])(smemc + 32768);
  const int tid = threadIdx.x;      // 0..511
  const int lane = tid & 63;
  const int v = tid >> 6;           // wave 0..7
  const int gate = v >> 1;
  const int ch = v & 1;             // col-half of the WG's 32 cols
  const int c = wgi >> 5;           // cluster 0..3 (batch rows c*16..+16)
  const int j = wgi & 31;           // WG in cluster (cols j*32..+32)
  const int b0 = c * 16, col0 = j * 32;
  const int l15 = lane & 15, g4 = lane >> 4;

  // Whh fragments: loaded ONCE, live across all 64 steps (128 VGPRs)
  short8 breg[32];
  {
    const u16* Brow = Whh + (size_t)(gate * 1024 + col0 + ch * 16 + l15) * 1024
                          + g4 * 8;
#pragma unroll
    for (int kk = 0; kk < 32; ++kk)
      breg[kk] = *(const short8*)(Brow + kk * 32);
  }

  // cell mapping: 512 threads = 16 rows x 32 cols
  const int crow = tid >> 5, colw = tid & 31;
  const int bg = b0 + crow, cgl = col0 + colw;
  const int ch2 = colw >> 4, cw = colw & 15;
  float creg = 0.f;

  // prologue: gate on first Xp chunk, then prefetch t=0
  if (xpdone) {
    if (tid == 0) {
      int guard = 0;
      while (__hip_atomic_load(&xpdone[0], __ATOMIC_RELAXED,
                               __HIP_MEMORY_SCOPE_AGENT) < 32u) {
        __builtin_amdgcn_s_sleep(2);
        if (++guard > (1 << 22)) break;
      }
    }
    __syncthreads();
  }
  float xg0, xg1, xg2, xg3;
  {
    size_t xrow = (size_t)bg * 4096 + cgl;
    xg0 = __builtin_nontemporal_load(&Xp[xrow]);
    xg1 = __builtin_nontemporal_load(&Xp[xrow + 1024]);
    xg2 = __builtin_nontemporal_load(&Xp[xrow + 2048]);
    xg3 = __builtin_nontemporal_load(&Xp[xrow + 3072]);
  }

  for (int t = 0; t < 64; ++t) {
    const char* rbase = (const char*)(hbuf + (size_t)(t & 1) * 65536)
                      + (size_t)b0 * 2048;
    u32* wb32 = (u32*)(hbuf + (size_t)((t + 1) & 1) * 65536);

    // ---- stage h slab (16 rows x 1024 cols) -> swizzled LDS, atomic loads
#pragma unroll
    for (int q = 0; q < 4; ++q) {
      int g = q * 512 + tid;              // 16B chunk id 0..2047
      int row = g >> 7;                   // 0..15
      int cb = (g & 127) * 16;            // byte col in row
      const u64* src = (const u64*)(rbase + (size_t)row * 2048 + cb);
      u64 lo = __hip_atomic_load(src,     __ATOMIC_RELAXED, __HIP_MEMORY_SCOPE_AGENT);
      u64 hi = __hip_atomic_load(src + 1, __ATOMIC_RELAXED, __HIP_MEMORY_SCOPE_AGENT);
      u64* d = (u64*)(smemA + row * 2048 + (cb ^ ((row & 7) << 4)));
      d[0] = lo; d[1] = hi;
    }
    __syncthreads();

    // ---- 32 MFMAs/wave (4 chains), A from swizzled LDS, B from regs
    f32x4 a4[4] = {(f32x4)0.f, (f32x4)0.f, (f32x4)0.f, (f32x4)0.f};
#pragma unroll
    for (int kk = 0; kk < 32; ++kk) {
      int cb2 = kk * 64 + g4 * 16;
      const short8 a = *(const short8*)(smemA + l15 * 2048 + (cb2 ^ ((l15 & 7) << 4)));
      a4[kk & 3] = __builtin_amdgcn_mfma_f32_16x16x32_bf16(a, breg[kk], a4[kk & 3], 0, 0, 0);
    }
    f32x4 asum = a4[0] + a4[1] + a4[2] + a4[3];
    {
      int m = g4 * 4;
#pragma unroll
      for (int e = 0; e < 4; ++e) lg[v][m + e][l15] = asum[e];
    }
    __syncthreads();

    // ---- cell update: 1 cell per thread (uses prefetched xg)
    {
      float gi = lg[0 + ch2][crow][cw] + xg0;
      float gf = lg[2 + ch2][crow][cw] + xg1;
      float gg = lg[4 + ch2][crow][cw] + xg2;
      float go = lg[6 + ch2][crow][cw] + xg3;
      float si = 1.f / (1.f + __expf(-gi));
      float sf = 1.f / (1.f + __expf(-gf));
      float so = 1.f / (1.f + __expf(-go));
      float tg = tanhf(gg);
      float cn = sf * creg + si * tg;
      float hn = so * tanhf(cn);
      creg = cn;
      u16 h16 = f2bf(hn);
      u32 mine = h16;
      u32 other = (u32)__shfl_xor((int)mine, 1);
      if (!(colw & 1)) {
        u32 pk = mine | (other << 16);
        __hip_atomic_store(wb32 + (((size_t)bg * 1024 + cgl) >> 1), pk,
                           __ATOMIC_RELAXED, __HIP_MEMORY_SCOPE_AGENT);
        if (hs_out)   // t-major, write-through (consumed intra-dispatch)
          __hip_atomic_store((u32*)hs_out + ((((size_t)t * 64 + bg) * 1024 + cgl) >> 1),
                             pk, __ATOMIC_RELAXED, __HIP_MEMORY_SCOPE_AGENT);
      }
      if (hT_out && t == 63) hT_out[bg * 1024 + cgl] = hn;   // cross-kernel
    }

    // ---- gate next Xp chunk (fused-producer mode), prefetch, barrier
    if (t != 63) {
      if (xpdone && (((t + 1) & 3) == 0)) {
        if (tid == 0) {
          int guard = 0;
          while (__hip_atomic_load(&xpdone[(t + 1) >> 2], __ATOMIC_RELAXED,
                                   __HIP_MEMORY_SCOPE_AGENT) < 32u) {
            __builtin_amdgcn_s_sleep(2);
            if (++guard > (1 << 22)) break;
          }
        }
        __syncthreads();
      }
      {
        size_t xrow = (size_t)((t + 1) * 64 + bg) * 4096 + cgl;
        xg0 = __builtin_nontemporal_load(&Xp[xrow]);
        xg1 = __builtin_nontemporal_load(&Xp[xrow + 1024]);
        xg2 = __builtin_nontemporal_load(&Xp[xrow + 2048]);
        xg3 = __builtin_nontemporal_load(&Xp[xrow + 3072]);
      }
      u32 want = (u32)(t + 1);
      asm volatile("s_waitcnt vmcnt(0)" ::: "memory");   // drains h/hsd stores + Xp
      __syncthreads();
      if (tid == 0)
        __hip_atomic_store(&arrive[wgi], want, __ATOMIC_RELAXED,
                           __HIP_MEMORY_SCOPE_AGENT);
      if (tid < 32) {
        int guard = 0;
        while (__hip_atomic_load(&arrive[c * 32 + tid], __ATOMIC_RELAXED,
                                 __HIP_MEMORY_SCOPE_AGENT) < want) {
          __builtin_amdgcn_s_sleep(2);
          if (++guard > (1 << 20)) break;   // safety valve
        }
      }
      __syncthreads();
      if (prog && j == 0 && tid == 0)
        __hip_atomic_store(&prog[c], want, __ATOMIC_RELAXED,
                           __HIP_MEMORY_SCOPE_AGENT);
    }
  }

  // ---- final drain + publish prog = 64 (decoder only)
  if (prog) {
    asm volatile("s_waitcnt vmcnt(0)" ::: "memory");
    __syncthreads();
    if (tid == 0)
      __hip_atomic_store(&arrive[wgi], 64u, __ATOMIC_RELAXED,
                         __HIP_MEMORY_SCOPE_AGENT);
    if (j == 0) {
      if (tid < 32) {
        int guard = 0;
        while (__hip_atomic_load(&arrive[c * 32 + tid], __ATOMIC_RELAXED,
                                 __HIP_MEMORY_SCOPE_AGENT) < 64u) {
          __builtin_amdgcn_s_sleep(2);
          if (++guard > (1 << 20)) break;
        }
      }
      __syncthreads();
      if (tid == 0)
        __hip_atomic_store(&prog[c], 64u, __ATOMIC_RELAXED,
                           __HIP_MEMORY_SCOPE_AGENT);
    }
  }
  __builtin_amdgcn_s_setprio(0);
}

// ---------------------------------------------------------------------------
// Standalone LSTM wrapper (fallback path).
__global__ __launch_bounds__(512, 1) void lstm_cluster(
    const u16* __restrict__ Whh, const float* __restrict__ Xp,
    u16* __restrict__ hbuf, float* __restrict__ hT_out, u32* arrive) {
  __shared__ __align__(16) char smem[40960];
  lstm_body(smem, Whh, Xp, hbuf, nullptr, hT_out, arrive, nullptr, nullptr,
            blockIdx.x);
}

__global__ __launch_bounds__(512) void gemm_bt0(
    const u16* __restrict__ A, const u16* __restrict__ B,
    float* __restrict__ C, const float* __restrict__ bias, int N, int K) {
  __shared__ __align__(16) char smem[49152];
  gemm0_body(smem, blockIdx.x, gridDim.x, A, B, C, bias, N, K);
}

// Fused encoder: 0..127 = encoder LSTM (gated on XpE progress); 128..255 =
// XpE producer (m-ordered, NT stores + done[] publish); 256..767 = XpD GEMM;
// 768..1279 = W_out conversion (grid-stride).
__global__ __launch_bounds__(512, 1) void enc_fused(
    const u16* __restrict__ whhN, float* __restrict__ XpE,
    u16* __restrict__ hbuf, float* __restrict__ hT_out, u32* arrive,
    u32* xpdone,
    const u16* __restrict__ Xe, const u16* __restrict__ wihN,
    const float* __restrict__ biasN,
    const u16* __restrict__ Xd, const u16* __restrict__ wihD,
    float* __restrict__ XpD, const float* __restrict__ biasD,
    const float* __restrict__ Wout, u16* __restrict__ wout) {
  __shared__ __align__(16) char smem[49152];
  if (blockIdx.x < 128) {
    lstm_body(smem, whhN, XpE, hbuf, nullptr, hT_out, arrive, nullptr, xpdone,
              blockIdx.x);
  } else if (blockIdx.x < 256) {
    xpe_producer(smem, blockIdx.x - 128, Xe, wihN, XpE, biasN, xpdone);
  } else if (blockIdx.x < 768) {
    gemm0_body(smem, blockIdx.x - 256, 512, Xd, wihD, XpD, biasD, 4096, 1024);
  } else {
    int tid0 = (blockIdx.x - 768) * 512 + threadIdx.x;
    for (int i = tid0; i < 8192000; i += 512 * 512) {
      float4 v = ((const float4*)Wout)[i];
      ushort4 o;
      o.x = f2bf(v.x); o.y = f2bf(v.y); o.z = f2bf(v.z); o.w = f2bf(v.w);
      ((ushort4*)wout)[i] = o;
    }
  }
}

// ---------------------------------------------------------------------------
// Fused decoder: blocks 0..127 = decoder LSTM (prio 2, t-major hsd + prog);
// blocks 128..4223 = logits GEMM, per-XCD n-partition, gated on prog, with
// 3-buffer counted-vmcnt pipeline (r22-proven). REMAP NT store out[b*64+t].
__global__ __launch_bounds__(512, 1) void dec_fused(
    const u16* __restrict__ whhD, const float* __restrict__ XpD,
    u16* __restrict__ hbuf, u16* __restrict__ hsd, u32* arrive, u32* prog,
    const u16* __restrict__ wout, float* __restrict__ out,
    const float* __restrict__ b_out) {
  __shared__ __align__(16) char smem[73728];   // 3x16KB A + 3x8KB B
  if (blockIdx.x < 128) {
    lstm_body(smem, whhD, XpD, hbuf, hsd, nullptr, arrive, prog, nullptr,
              blockIdx.x);
    return;
  }
  // ---- logits GEMM part
  u16 (*lA)[256 * 32] = (u16(*)[256 * 32])smem;            // 3 bufs
  u16 (*lB)[128 * 32] = (u16(*)[128 * 32])(smem + 49152);  // 3 bufs
  const int tid = threadIdx.x;
  const int lane = tid & 63;
  const int wid = tid >> 6;

  const int i = blockIdx.x - 128;  // 0..4095
  const int x = i & 7;             // XCD id
  const int k = i >> 3;
  const int mg = k >> 6;
  const int r  = k & 63;
  const int kn = r >> 1;
  const int mi = r & 1;
  const int tn = kn * 8 + x;
  if (tn >= 250) return;           // dummy (whole WG exits)
  const int mt = mg * 2 + mi;      // m-tile = t-chunk [mt*4, mt*4+4)
  const int tile_m = mt * 256;
  const int tile_n = tn * 128;
  const int wm = wid >> 1, wn = wid & 1;
  const int N = 32000, K = 1024;

  // ---- wait until decoder steps 0..mt*4+3 are complete in all clusters
  {
    u32 need = (u32)(mt * 4 + 4);
    if (tid < 4) {
      int guard = 0;
      while (__hip_atomic_load(&prog[tid], __ATOMIC_RELAXED,
                               __HIP_MEMORY_SCOPE_AGENT) < need) {
        __builtin_amdgcn_s_sleep(8);
        if (++guard > (1 << 22)) break;   // safety valve
      }
    }
    __syncthreads();
  }

  const int ldr = lane >> 2;
  const int lko = (lane & 3) * 8;
  const int l15 = lane & 15;
  const int g4 = lane >> 4;

  const size_t aBase = (size_t)tile_m * K;
  const size_t bBase = (size_t)tile_n * K;

  auto stg = [&](int buf, int k0) {
#pragma unroll
    for (int q = 0; q < 2; ++q) {
      int chk = wid * 2 + q;
      int row = chk * 16 + ldr;
      GLD16(hsd + aBase + (size_t)row * K + k0 + lko, &lA[buf][chk * 512]);
    }
    int row = wid * 16 + ldr;
    GLD16(wout + bBase + (size_t)row * K + k0 + lko, &lB[buf][wid * 512]);
  };

  f32x4 acc[4][4];
#pragma unroll
  for (int i2 = 0; i2 < 4; ++i2)
#pragma unroll
    for (int j2 = 0; j2 < 4; ++j2) acc[i2][j2] = (f32x4)0.f;

  stg(0, 0);                           // prologue: tile 0 in flight

  const int NIT = K >> 5;              // 32
  for (int it = 0; it < NIT; ++it) {
    const int cur = it % 3;
    if (it + 1 < NIT) {
      stg((it + 1) % 3, (it + 1) * 32);
      asm volatile("s_waitcnt vmcnt(3)" ::: "memory");  // tile it landed
    } else {
      asm volatile("s_waitcnt vmcnt(0)" ::: "memory");  // last tile: drain
    }
    __builtin_amdgcn_s_barrier();
    short8 af[4], bf[4];
#pragma unroll
    for (int i2 = 0; i2 < 4; ++i2)
      af[i2] = *(const short8*)&lA[cur][(wm * 64 + i2 * 16 + l15) * 32 + g4 * 8];
#pragma unroll
    for (int j2 = 0; j2 < 4; ++j2)
      bf[j2] = *(const short8*)&lB[cur][(wn * 64 + j2 * 16 + l15) * 32 + g4 * 8];
#pragma unroll
    for (int i2 = 0; i2 < 4; ++i2)
#pragma unroll
      for (int j2 = 0; j2 < 4; ++j2)
        acc[i2][j2] = __builtin_amdgcn_mfma_f32_16x16x32_bf16(af[i2], bf[j2], acc[i2][j2], 0, 0, 0);
  }

#pragma unroll
  for (int i2 = 0; i2 < 4; ++i2) {
    int row0 = tile_m + wm * 64 + i2 * 16 + (g4 << 2);
#pragma unroll
    for (int j2 = 0; j2 < 4; ++j2) {
      int col = tile_n + wn * 64 + j2 * 16 + l15;
      float bv = b_out[col];
#pragma unroll
      for (int e = 0; e < 4; ++e) {
        int rr = row0 + e;                       // t-major row = t*64+b
        size_t o = (size_t)((rr & 63) * 64 + (rr >> 6)) * (size_t)N + col;
        __builtin_nontemporal_store(acc[i2][j2][e] + bv, &out[o]);
      }
    }
  }
}

// ---------------------------------------------------------------------------
// mean/logvar/latent + hd0 = [latent|cond_e] @ W_st^T + b_st -> bf16 h0.
__global__ __launch_bounds__(256) void latent_hd0_kernel(
    const float* hT, const float* Wm, const float* bm,
    const float* Wl, const float* bl, const float* Wst, const float* bst,
    const float* eps, const float* ce, u16* hb0) {
  __shared__ float red[64][4];
  __shared__ float ml[64];
  __shared__ float lat[40];
  int b = blockIdx.x;
  int tid = threadIdx.x;
  int o = tid >> 2, p = tid & 3;
  const float* w = (o < 32) ? (Wm + (size_t)o * 1024) : (Wl + (size_t)(o - 32) * 1024);
  const float* h = hT + (size_t)b * 1024;
  float s = 0.f;
  for (int k = p * 256; k < p * 256 + 256; ++k) s += h[k] * w[k];
  red[o][p] = s;
  __syncthreads();
  if (tid < 64) {
    float v = red[tid][0] + red[tid][1] + red[tid][2] + red[tid][3];
    v += (tid < 32) ? bm[tid] : bl[tid - 32];
    ml[tid] = v;
  }
  __syncthreads();
  if (tid < 32) lat[tid] = eps[b * 32 + tid] * __expf(0.5f * ml[32 + tid]) + ml[tid];
  if (tid >= 32 && tid < 40) lat[tid] = ce[b * 8 + (tid - 32)];
  __syncthreads();
  for (int hc = tid; hc < 1024; hc += 256) {
    float s2 = bst[hc];
    const float* wr = Wst + (size_t)hc * 40;
#pragma unroll
    for (int j = 0; j < 40; ++j) s2 += lat[j] * wr[j];
    hb0[b * 1024 + hc] = f2bf(s2);
  }
}

// ---------------------------------------------------------------------------
extern "C" void kernel_launch(void* const* d_in, const int* in_sizes, int n_in,
                              void* d_out, int out_size, void* d_ws, size_t ws_size,
                              hipStream_t stream) {
  const int*   input_word = (const int*)d_in[0];
  const int*   cond       = (const int*)d_in[1];
  const float* emb_N      = (const float*)d_in[2];
  const float* Wih_N      = (const float*)d_in[3];
  const float* Whh_N      = (const float*)d_in[4];
  const float* bih_N      = (const float*)d_in[5];
  const float* bhh_N      = (const float*)d_in[6];
  const float* emb_D      = (const float*)d_in[7];
  const float* Wih_D      = (const float*)d_in[8];
  const float* Whh_D      = (const float*)d_in[9];
  const float* bih_D      = (const float*)d_in[10];
  const float* bhh_D      = (const float*)d_in[11];
  const float* emb_cond   = (const float*)d_in[12];
  const float* W_mean     = (const float*)d_in[13];
  const float* b_mean     = (const float*)d_in[14];
  const float* W_logvar   = (const float*)d_in[15];
  const float* b_logvar   = (const float*)d_in[16];
  const float* W_st       = (const float*)d_in[17];
  const float* b_st       = (const float*)d_in[18];
  const float* W_out      = (const float*)d_in[19];
  const float* b_out      = (const float*)d_in[20];
  const float* eps        = (const float*)d_in[21];
  float* out = (float*)d_out;

  char* ws = (char*)d_ws;
  size_t off = 0;
  auto alloc = [&](size_t b) { size_t p = off; off += (b + 255) & ~(size_t)255; return p; };
  u16*   wihN = (u16*)(ws + alloc(4096ull * 1024 * 2));
  u16*   whhN = (u16*)(ws + alloc(4096ull * 1024 * 2));
  u16*   wihD = (u16*)(ws + alloc(4096ull * 1024 * 2));
  u16*   whhD = (u16*)(ws + alloc(4096ull * 1024 * 2));
  u16*   wout = (u16*)(ws + alloc(32000ull * 1024 * 2));
  u16*   Xe   = (u16*)(ws + alloc(4096ull * 1024 * 2));
  u16*   Xd   = (u16*)(ws + alloc(4096ull * 1024 * 2));
  float* Xp   = (float*)(ws + alloc(4096ull * 4096 * 4));   // enc (and dec fallback)
  u16*   hsd  = (u16*)(ws + alloc(4096ull * 1024 * 2));     // T-MAJOR [t*64+b][1024]
  u16*   hb   = (u16*)(ws + alloc(2ull * 64 * 1024 * 2));   // bf16 h dbuf
  float* hf   = (float*)(ws + alloc(64ull * 1024 * 4));     // fp32 h_T (encoder)
  float* biasN = (float*)(ws + alloc(4096 * 4));
  float* biasD = (float*)(ws + alloc(4096 * 4));
  float* ce    = (float*)(ws + alloc(64 * 8 * 4));
  u32*   bar   = (u32*)(ws + alloc(4096));
  // bar: enc arrive [0..127], dec arrive [256..383], dec prog [512..515],
  //      XpE done [768..783]
  size_t base_off = off;
  float* XpD2 = (float*)(ws + alloc(4096ull * 4096 * 4));   // dec Xp (fused path)
  if (base_off > ws_size) return;
  const bool fused = (off <= ws_size);
  float* XpD = fused ? XpD2 : Xp;

  // front-end: weights conv + prep + gathers + h0 init, one launch
  front_all<<<24854, 256, 0, stream>>>(Wih_N, wihN, Whh_N, whhN,
                                       Wih_D, wihD, Whh_D, whhD,
                                       cond, emb_cond,
                                       bih_N, bhh_N, bih_D, bhh_D,
                                       ce, biasN, biasD, bar,
                                       emb_N, emb_D, input_word, Xe, Xd, hb);

  if (fused) {
    // encoder LSTM + XpE producer + decoder-Xp GEMM + W_out conv, one launch
    enc_fused<<<1280, 512, 0, stream>>>(whhN, Xp, hb, hf, bar + 0, bar + 768,
                                        Xe, wihN, biasN,
                                        Xd, wihD, XpD, biasD, W_out, wout);
  } else {
    gemm_bt0<<<512, 512, 0, stream>>>(Xe, wihN, Xp, biasN, 4096, 1024);
    conv_wout<<<32000, 256, 0, stream>>>(W_out, wout);
    lstm_cluster<<<128, 512, 0, stream>>>(whhN, Xp, hb, hf, bar + 0);
  }
  // latent + decoder h0
  latent_hd0_kernel<<<64, 256, 0, stream>>>(hf, W_mean, b_mean, W_logvar, b_logvar,
                                            W_st, b_st, eps, ce, hb);
  if (!fused)
    gemm_bt0<<<512, 512, 0, stream>>>(Xd, wihD, XpD, biasD, 4096, 1024);
  // decoder LSTM + logits GEMM fused (producer-consumer on hsd via prog[])
  dec_fused<<<4224, 512, 0, stream>>>(whhD, XpD, hb, hsd, bar + 256, bar + 512,
                                      wout, out, b_out);
}

// Round 24
// 890.739 us; speedup vs baseline: 1.1649x; 1.0515x over previous
//
#include <hip/hip_runtime.h>
#include <hip/hip_bf16.h>

typedef unsigned short u16;
typedef unsigned int   u32;
typedef unsigned long long u64;
typedef __attribute__((ext_vector_type(8))) short short8;   // 8 x bf16 (4 VGPRs)
typedef __attribute__((ext_vector_type(4))) float f32x4;

#define DEVINL static __device__ __forceinline__

// round-to-nearest-even f32 -> bf16
DEVINL u16 f2bf(float x) {
  u32 u = __float_as_uint(x);
  u32 r = (u + 0x7fffu + ((u >> 16) & 1u)) >> 16;
  return (u16)r;
}

// async global->LDS, 16B per lane. LDS dest = uniform base + lane*16.
#define GLD16(gp, lp) __builtin_amdgcn_global_load_lds(                     \
    (const __attribute__((address_space(1))) u32*)(gp),                     \
    (__attribute__((address_space(3))) u32*)(lp), 16, 0, 0)

// ---------------------------------------------------------------------------
// FRONT-END, one segmented launch: conv4 | prep | gatherE | gatherD | init.
__global__ __launch_bounds__(256) void front_all(
    const float* __restrict__ s0, u16* __restrict__ d0,
    const float* __restrict__ s1, u16* __restrict__ d1,
    const float* __restrict__ s2, u16* __restrict__ d2,
    const float* __restrict__ s3, u16* __restrict__ d3,
    const int* __restrict__ cond, const float* __restrict__ emb_cond,
    const float* __restrict__ bihN, const float* __restrict__ bhhN,
    const float* __restrict__ bihD, const float* __restrict__ bhhD,
    float* __restrict__ ce, float* __restrict__ biasN, float* __restrict__ biasD,
    u32* __restrict__ bar,
    const float* __restrict__ embN, const float* __restrict__ embD,
    const int* __restrict__ words, u16* __restrict__ Xe, u16* __restrict__ Xd,
    u16* __restrict__ hb0) {
  int blk = blockIdx.x;
  if (blk < 16384) {                       // ---- weight conversion (4x 4Kx1K)
    int p = blk >> 12, local = blk & 4095;
    const float* s = (p == 0) ? s0 : (p == 1) ? s1 : (p == 2) ? s2 : s3;
    u16*         d = (p == 0) ? d0 : (p == 1) ? d1 : (p == 2) ? d2 : d3;
    int i = local * 256 + threadIdx.x;
    float4 v = ((const float4*)s)[i];
    ushort4 o;
    o.x = f2bf(v.x); o.y = f2bf(v.y); o.z = f2bf(v.z); o.w = f2bf(v.w);
    ((ushort4*)d)[i] = o;
  } else if (blk < 16406) {                // ---- prep (ce, biases, barriers)
    int tid = (blk - 16384) * 256 + threadIdx.x;
    if (tid < 512) {
      int b = tid >> 3, j = tid & 7;
      ce[tid] = emb_cond[cond[b] * 8 + j];
    }
    int i = tid - 512;
    if (i >= 0 && i < 4096) {
      biasN[i] = bihN[i] + bhhN[i];
      biasD[i] = bihD[i] + bhhD[i];
    }
    int k = tid - 4608;
    if (k >= 0 && k < 1024) bar[k] = 0;
  } else if (blk < 24598) {                // ---- embedding gathers
    int dec = (blk >= 20502);
    int r = blk - (dec ? 20502 : 16406);   // r = t*64 + b
    int t = r >> 6, b = r & 63;
    int tok = dec ? ((t == 0) ? 0 : words[b * 64 + t - 1]) : words[b * 64 + t];
    const float* emb = dec ? embD : embN;
    u16* X = dec ? Xd : Xe;
    float4 v = ((const float4*)(emb + (size_t)tok * 1024))[threadIdx.x];
    ushort4 o;
    o.x = f2bf(v.x); o.y = f2bf(v.y); o.z = f2bf(v.z); o.w = f2bf(v.w);
    ((ushort4*)(X + (size_t)r * 1024))[threadIdx.x] = o;
  } else {                                 // ---- encoder h0
    int tid = (blk - 24598) * 256 + threadIdx.x;   // 64*1024
    int b = tid >> 10, col = tid & 1023;
    float v = (col >= 1016) ? emb_cond[cond[b] * 8 + (col - 1016)] : 0.f;
    hb0[tid] = f2bf(v);
  }
}

// standalone W_out conversion (fallback path only)
__global__ __launch_bounds__(256) void conv_wout(const float* __restrict__ s,
                                                 u16* __restrict__ d) {
  int i = blockIdx.x * 256 + threadIdx.x;
  float4 v = ((const float4*)s)[i];
  ushort4 o;
  o.x = f2bf(v.x); o.y = f2bf(v.y); o.z = f2bf(v.z); o.w = f2bf(v.w);
  ((ushort4*)d)[i] = o;
}

// ---------------------------------------------------------------------------
// GEMM body, MODE-0 style (n-fast + bijective XCD swizzle), 256x128 tile,
// BK=32, 512 threads = 8 waves (4m x 2n), double-buffered LDS (48KB).
DEVINL void gemm0_body(char* smemc, int bid, int nwg,
                       const u16* __restrict__ A, const u16* __restrict__ B,
                       float* __restrict__ C, const float* __restrict__ bias,
                       int N, int K) {
  u16 (*lA)[256 * 32] = (u16(*)[256 * 32])smemc;
  u16 (*lB)[128 * 32] = (u16(*)[128 * 32])(smemc + 32768);
  const int tid = threadIdx.x;
  const int lane = tid & 63;
  const int wid = tid >> 6;

  const int nn = N >> 7;
  const int wgid = (bid & 7) * (nwg >> 3) + (bid >> 3);
  const int tile_m = (wgid / nn) * 256;
  const int tile_n = (wgid % nn) * 128;
  const int wm = wid >> 1, wn = wid & 1;

  const int ldr = lane >> 2;
  const int lko = (lane & 3) * 8;
  const int l15 = lane & 15;
  const int g4 = lane >> 4;

  const size_t aBase = (size_t)tile_m * K;
  const size_t bBase = (size_t)tile_n * K;

  auto stage = [&](int buf, int k0) {
#pragma unroll
    for (int q = 0; q < 2; ++q) {
      int chk = wid * 2 + q;
      int row = chk * 16 + ldr;
      GLD16(A + aBase + (size_t)row * K + k0 + lko, &lA[buf][chk * 512]);
    }
    int row = wid * 16 + ldr;
    GLD16(B + bBase + (size_t)row * K + k0 + lko, &lB[buf][wid * 512]);
  };

  f32x4 acc[4][4];
#pragma unroll
  for (int i = 0; i < 4; ++i)
#pragma unroll
    for (int j = 0; j < 4; ++j) acc[i][j] = (f32x4)0.f;

  stage(0, 0);
  __syncthreads();

  const int NIT = K >> 5;
  for (int it = 0; it < NIT; ++it) {
    const int cur = it & 1;
    if (it + 1 < NIT) stage(cur ^ 1, (it + 1) * 32);
    short8 af[4], bf[4];
#pragma unroll
    for (int i = 0; i < 4; ++i)
      af[i] = *(const short8*)&lA[cur][(wm * 64 + i * 16 + l15) * 32 + g4 * 8];
#pragma unroll
    for (int j = 0; j < 4; ++j)
      bf[j] = *(const short8*)&lB[cur][(wn * 64 + j * 16 + l15) * 32 + g4 * 8];
#pragma unroll
    for (int i = 0; i < 4; ++i)
#pragma unroll
      for (int j = 0; j < 4; ++j)
        acc[i][j] = __builtin_amdgcn_mfma_f32_16x16x32_bf16(af[i], bf[j], acc[i][j], 0, 0, 0);
    __syncthreads();
  }

#pragma unroll
  for (int i = 0; i < 4; ++i) {
    int row0 = tile_m + wm * 64 + i * 16 + (g4 << 2);
#pragma unroll
    for (int j = 0; j < 4; ++j) {
      int col = tile_n + wn * 64 + j * 16 + l15;
      float bv = bias[col];
#pragma unroll
      for (int e = 0; e < 4; ++e)
        C[(size_t)(row0 + e) * (size_t)N + col] = acc[i][j][e] + bv;
    }
  }
}

// ---------------------------------------------------------------------------
// XpE PRODUCER: 128 blocks; block p owns n-panel (p&31) and walks m-tiles
// mt = r*4 + (p>>5), r=0..3 — t-chunks 0..3 complete after round one.
// NT stores (write-through) + vmcnt(0) + atomicAdd done[mt] (release).
DEVINL void xpe_producer(char* smemc, int p,
                         const u16* __restrict__ Xe, const u16* __restrict__ W,
                         float* __restrict__ Xp, const float* __restrict__ bias,
                         u32* __restrict__ done) {
  u16 (*lA)[256 * 32] = (u16(*)[256 * 32])smemc;
  u16 (*lB)[128 * 32] = (u16(*)[128 * 32])(smemc + 32768);
  const int tid = threadIdx.x;
  const int lane = tid & 63;
  const int wid = tid >> 6;
  const int n = p & 31, mq = p >> 5;
  const int wm = wid >> 1, wn = wid & 1;
  const int ldr = lane >> 2;
  const int lko = (lane & 3) * 8;
  const int l15 = lane & 15;
  const int g4 = lane >> 4;
  const int N = 4096, K = 1024;
  const int tile_n = n * 128;
  const size_t bBase = (size_t)tile_n * K;

  for (int r2 = 0; r2 < 4; ++r2) {
    const int mt = r2 * 4 + mq;
    const int tile_m = mt * 256;
    const size_t aBase = (size_t)tile_m * K;

    auto stage = [&](int buf, int k0) {
#pragma unroll
      for (int q = 0; q < 2; ++q) {
        int chk = wid * 2 + q;
        int row = chk * 16 + ldr;
        GLD16(Xe + aBase + (size_t)row * K + k0 + lko, &lA[buf][chk * 512]);
      }
      int row = wid * 16 + ldr;
      GLD16(W + bBase + (size_t)row * K + k0 + lko, &lB[buf][wid * 512]);
    };

    f32x4 acc[4][4];
#pragma unroll
    for (int i = 0; i < 4; ++i)
#pragma unroll
      for (int j = 0; j < 4; ++j) acc[i][j] = (f32x4)0.f;

    stage(0, 0);
    __syncthreads();
    const int NIT = K >> 5;
    for (int it = 0; it < NIT; ++it) {
      const int cur = it & 1;
      if (it + 1 < NIT) stage(cur ^ 1, (it + 1) * 32);
      short8 af[4], bf[4];
#pragma unroll
      for (int i = 0; i < 4; ++i)
        af[i] = *(const short8*)&lA[cur][(wm * 64 + i * 16 + l15) * 32 + g4 * 8];
#pragma unroll
      for (int j = 0; j < 4; ++j)
        bf[j] = *(const short8*)&lB[cur][(wn * 64 + j * 16 + l15) * 32 + g4 * 8];
#pragma unroll
      for (int i = 0; i < 4; ++i)
#pragma unroll
        for (int j = 0; j < 4; ++j)
          acc[i][j] = __builtin_amdgcn_mfma_f32_16x16x32_bf16(af[i], bf[j], acc[i][j], 0, 0, 0);
      __syncthreads();
    }

#pragma unroll
    for (int i = 0; i < 4; ++i) {
      int row0 = tile_m + wm * 64 + i * 16 + (g4 << 2);
#pragma unroll
      for (int j = 0; j < 4; ++j) {
        int col = tile_n + wn * 64 + j * 16 + l15;
        float bv = bias[col];
#pragma unroll
        for (int e = 0; e < 4; ++e)
          __builtin_nontemporal_store(acc[i][j][e] + bv,
                                      &Xp[(size_t)(row0 + e) * (size_t)N + col]);
      }
    }
    asm volatile("s_waitcnt vmcnt(0)" ::: "memory");   // NT stores at coh point
    __syncthreads();
    if (tid == 0)
      __hip_atomic_fetch_add(&done[mt], 1u, __ATOMIC_RELEASE,
                             __HIP_MEMORY_SCOPE_AGENT);
    __syncthreads();
  }
}

// ---------------------------------------------------------------------------
// CLUSTERED PERSISTENT LSTM body (proven skeleton). If prog != null
// (decoder): hs_out is T-MAJOR via packed-u32 agent-atomic stores; j==0 WG
// publishes prog[c] per step. If xpdone != null: gate each 4-step Xp
// prefetch window on done[chunk] == 32.
DEVINL void lstm_body(char* smemc, const u16* __restrict__ Whh,
                      const float* __restrict__ Xp, u16* __restrict__ hbuf,
                      u16* __restrict__ hs_out, float* __restrict__ hT_out,
                      u32* arrive, u32* prog, u32* xpdone, int wgi) {
  __builtin_amdgcn_s_setprio(2);
  char* smemA = smemc;
  float (*lg)[16][16] = (float(*)[16][16])(smemc + 32768);
  const int tid = threadIdx.x;      // 0..511
  const int lane = tid & 63;
  const int v = tid >> 6;           // wave 0..7
  const int gate = v >> 1;
  const int ch = v & 1;             // col-half of the WG's 32 cols
  const int c = wgi >> 5;           // cluster 0..3 (batch rows c*16..+16)
  const int j = wgi & 31;           // WG in cluster (cols j*32..+32)
  const int b0 = c * 16, col0 = j * 32;
  const int l15 = lane & 15, g4 = lane >> 4;

  // Whh fragments: loaded ONCE, live across all 64 steps (128 VGPRs)
  short8 breg[32];
  {
    const u16* Brow = Whh + (size_t)(gate * 1024 + col0 + ch * 16 + l15) * 1024
                          + g4 * 8;
#pragma unroll
    for (int kk = 0; kk < 32; ++kk)
      breg[kk] = *(const short8*)(Brow + kk * 32);
  }

  // cell mapping: 512 threads = 16 rows x 32 cols
  const int crow = tid >> 5, colw = tid & 31;
  const int bg = b0 + crow, cgl = col0 + colw;
  const int ch2 = colw >> 4, cw = colw & 15;
  float creg = 0.f;

  // prologue: gate on first Xp chunk, then prefetch t=0
  if (xpdone) {
    if (tid == 0) {
      int guard = 0;
      while (__hip_atomic_load(&xpdone[0], __ATOMIC_RELAXED,
                               __HIP_MEMORY_SCOPE_AGENT) < 32u) {
        __builtin_amdgcn_s_sleep(2);
        if (++guard > (1 << 22)) break;
      }
    }
    __syncthreads();
  }
  float xg0, xg1, xg2, xg3;
  {
    size_t xrow = (size_t)bg * 4096 + cgl;
    xg0 = __builtin_nontemporal_load(&Xp[xrow]);
    xg1 = __builtin_nontemporal_load(&Xp[xrow + 1024]);
    xg2 = __builtin_nontemporal_load(&Xp[xrow + 2048]);
    xg3 = __builtin_nontemporal_load(&Xp[xrow + 3072]);
  }

  for (int t = 0; t < 64; ++t) {
    const char* rbase = (const char*)(hbuf + (size_t)(t & 1) * 65536)
                      + (size_t)b0 * 2048;
    u32* wb32 = (u32*)(hbuf + (size_t)((t + 1) & 1) * 65536);

    // ---- stage h slab (16 rows x 1024 cols) -> swizzled LDS, atomic loads
#pragma unroll
    for (int q = 0; q < 4; ++q) {
      int g = q * 512 + tid;              // 16B chunk id 0..2047
      int row = g >> 7;                   // 0..15
      int cb = (g & 127) * 16;            // byte col in row
      const u64* src = (const u64*)(rbase + (size_t)row * 2048 + cb);
      u64 lo = __hip_atomic_load(src,     __ATOMIC_RELAXED, __HIP_MEMORY_SCOPE_AGENT);
      u64 hi = __hip_atomic_load(src + 1, __ATOMIC_RELAXED, __HIP_MEMORY_SCOPE_AGENT);
      u64* d = (u64*)(smemA + row * 2048 + (cb ^ ((row & 7) << 4)));
      d[0] = lo; d[1] = hi;
    }
    __syncthreads();

    // ---- 32 MFMAs/wave (4 chains), A from swizzled LDS, B from regs
    f32x4 a4[4] = {(f32x4)0.f, (f32x4)0.f, (f32x4)0.f, (f32x4)0.f};
#pragma unroll
    for (int kk = 0; kk < 32; ++kk) {
      int cb2 = kk * 64 + g4 * 16;
      const short8 a = *(const short8*)(smemA + l15 * 2048 + (cb2 ^ ((l15 & 7) << 4)));
      a4[kk & 3] = __builtin_amdgcn_mfma_f32_16x16x32_bf16(a, breg[kk], a4[kk & 3], 0, 0, 0);
    }
    f32x4 asum = a4[0] + a4[1] + a4[2] + a4[3];
    {
      int m = g4 * 4;
#pragma unroll
      for (int e = 0; e < 4; ++e) lg[v][m + e][l15] = asum[e];
    }
    __syncthreads();

    // ---- cell update: 1 cell per thread (uses prefetched xg)
    {
      float gi = lg[0 + ch2][crow][cw] + xg0;
      float gf = lg[2 + ch2][crow][cw] + xg1;
      float gg = lg[4 + ch2][crow][cw] + xg2;
      float go = lg[6 + ch2][crow][cw] + xg3;
      float si = 1.f / (1.f + __expf(-gi));
      float sf = 1.f / (1.f + __expf(-gf));
      float so = 1.f / (1.f + __expf(-go));
      float tg = tanhf(gg);
      float cn = sf * creg + si * tg;
      float hn = so * tanhf(cn);
      creg = cn;
      u16 h16 = f2bf(hn);
      u32 mine = h16;
      u32 other = (u32)__shfl_xor((int)mine, 1);
      if (!(colw & 1)) {
        u32 pk = mine | (other << 16);
        __hip_atomic_store(wb32 + (((size_t)bg * 1024 + cgl) >> 1), pk,
                           __ATOMIC_RELAXED, __HIP_MEMORY_SCOPE_AGENT);
        if (hs_out)   // t-major, write-through (consumed intra-dispatch)
          __hip_atomic_store((u32*)hs_out + ((((size_t)t * 64 + bg) * 1024 + cgl) >> 1),
                             pk, __ATOMIC_RELAXED, __HIP_MEMORY_SCOPE_AGENT);
      }
      if (hT_out && t == 63) hT_out[bg * 1024 + cgl] = hn;   // cross-kernel
    }

    // ---- gate next Xp chunk (fused-producer mode), prefetch, barrier
    if (t != 63) {
      if (xpdone && (((t + 1) & 3) == 0)) {
        if (tid == 0) {
          int guard = 0;
          while (__hip_atomic_load(&xpdone[(t + 1) >> 2], __ATOMIC_RELAXED,
                                   __HIP_MEMORY_SCOPE_AGENT) < 32u) {
            __builtin_amdgcn_s_sleep(2);
            if (++guard > (1 << 22)) break;
          }
        }
        __syncthreads();
      }
      {
        size_t xrow = (size_t)((t + 1) * 64 + bg) * 4096 + cgl;
        xg0 = __builtin_nontemporal_load(&Xp[xrow]);
        xg1 = __builtin_nontemporal_load(&Xp[xrow + 1024]);
        xg2 = __builtin_nontemporal_load(&Xp[xrow + 2048]);
        xg3 = __builtin_nontemporal_load(&Xp[xrow + 3072]);
      }
      u32 want = (u32)(t + 1);
      asm volatile("s_waitcnt vmcnt(0)" ::: "memory");   // drains h/hsd stores + Xp
      __syncthreads();
      if (tid == 0)
        __hip_atomic_store(&arrive[wgi], want, __ATOMIC_RELAXED,
                           __HIP_MEMORY_SCOPE_AGENT);
      if (tid < 32) {
        int guard = 0;
        while (__hip_atomic_load(&arrive[c * 32 + tid], __ATOMIC_RELAXED,
                                 __HIP_MEMORY_SCOPE_AGENT) < want) {
          __builtin_amdgcn_s_sleep(2);
          if (++guard > (1 << 20)) break;   // safety valve
        }
      }
      __syncthreads();
      if (prog && j == 0 && tid == 0)
        __hip_atomic_store(&prog[c], want, __ATOMIC_RELAXED,
                           __HIP_MEMORY_SCOPE_AGENT);
    }
  }

  // ---- final drain + publish prog = 64 (decoder only)
  if (prog) {
    asm volatile("s_waitcnt vmcnt(0)" ::: "memory");
    __syncthreads();
    if (tid == 0)
      __hip_atomic_store(&arrive[wgi], 64u, __ATOMIC_RELAXED,
                         __HIP_MEMORY_SCOPE_AGENT);
    if (j == 0) {
      if (tid < 32) {
        int guard = 0;
        while (__hip_atomic_load(&arrive[c * 32 + tid], __ATOMIC_RELAXED,
                                 __HIP_MEMORY_SCOPE_AGENT) < 64u) {
          __builtin_amdgcn_s_sleep(2);
          if (++guard > (1 << 20)) break;
        }
      }
      __syncthreads();
      if (tid == 0)
        __hip_atomic_store(&prog[c], 64u, __ATOMIC_RELAXED,
                           __HIP_MEMORY_SCOPE_AGENT);
    }
  }
  __builtin_amdgcn_s_setprio(0);
}

// ---------------------------------------------------------------------------
// Standalone LSTM wrapper (fallback path).
__global__ __launch_bounds__(512, 1) void lstm_cluster(
    const u16* __restrict__ Whh, const float* __restrict__ Xp,
    u16* __restrict__ hbuf, float* __restrict__ hT_out, u32* arrive) {
  __shared__ __align__(16) char smem[40960];
  lstm_body(smem, Whh, Xp, hbuf, nullptr, hT_out, arrive, nullptr, nullptr,
            blockIdx.x);
}

__global__ __launch_bounds__(512) void gemm_bt0(
    const u16* __restrict__ A, const u16* __restrict__ B,
    float* __restrict__ C, const float* __restrict__ bias, int N, int K) {
  __shared__ __align__(16) char smem[49152];
  gemm0_body(smem, blockIdx.x, gridDim.x, A, B, C, bias, N, K);
}

// Fused encoder: 0..127 = encoder LSTM (gated on XpE progress); 128..255 =
// XpE producer; 256..767 = XpD GEMM; 768..1279 = W_out conversion.
__global__ __launch_bounds__(512, 1) void enc_fused(
    const u16* __restrict__ whhN, float* __restrict__ XpE,
    u16* __restrict__ hbuf, float* __restrict__ hT_out, u32* arrive,
    u32* xpdone,
    const u16* __restrict__ Xe, const u16* __restrict__ wihN,
    const float* __restrict__ biasN,
    const u16* __restrict__ Xd, const u16* __restrict__ wihD,
    float* __restrict__ XpD, const float* __restrict__ biasD,
    const float* __restrict__ Wout, u16* __restrict__ wout) {
  __shared__ __align__(16) char smem[49152];
  if (blockIdx.x < 128) {
    lstm_body(smem, whhN, XpE, hbuf, nullptr, hT_out, arrive, nullptr, xpdone,
              blockIdx.x);
  } else if (blockIdx.x < 256) {
    xpe_producer(smem, blockIdx.x - 128, Xe, wihN, XpE, biasN, xpdone);
  } else if (blockIdx.x < 768) {
    gemm0_body(smem, blockIdx.x - 256, 512, Xd, wihD, XpD, biasD, 4096, 1024);
  } else {
    int tid0 = (blockIdx.x - 768) * 512 + threadIdx.x;
    for (int i = tid0; i < 8192000; i += 512 * 512) {
      float4 v = ((const float4*)Wout)[i];
      ushort4 o;
      o.x = f2bf(v.x); o.y = f2bf(v.y); o.z = f2bf(v.z); o.w = f2bf(v.w);
      ((ushort4*)wout)[i] = o;
    }
  }
}

// ---------------------------------------------------------------------------
// Fused decoder: blocks 0..127 = decoder LSTM (prio 2, t-major hsd + prog);
// blocks 128..2175 = logits GEMM with 256x256 TILE (halves staged B-bytes
// per output: 3.15GB -> 2.10GB through L2 — the measured staging-BW bound),
// 8 waves 2m x 4n (per-wave 128x64, acc[8][4]), 3-buffer counted-vmcnt
// pipeline (vmcnt(4): 4 GLD16/thread per tile), per-XCD n-partition, gated
// on prog (m-tile = 256 rows = exactly 4 t-steps). REMAP NT stores.
__global__ __launch_bounds__(512, 1) void dec_fused(
    const u16* __restrict__ whhD, const float* __restrict__ XpD,
    u16* __restrict__ hbuf, u16* __restrict__ hsd, u32* arrive, u32* prog,
    const u16* __restrict__ wout, float* __restrict__ out,
    const float* __restrict__ b_out) {
  __shared__ __align__(16) char smem[98304];   // 3 x (16KB A + 16KB B)
  if (blockIdx.x < 128) {
    lstm_body(smem, whhD, XpD, hbuf, hsd, nullptr, arrive, prog, nullptr,
              blockIdx.x);
    return;
  }
  // ---- logits GEMM part, 256x256 tile
  u16 (*lA)[256 * 32] = (u16(*)[256 * 32])smem;            // 3 bufs
  u16 (*lB)[256 * 32] = (u16(*)[256 * 32])(smem + 49152);  // 3 bufs
  const int tid = threadIdx.x;
  const int lane = tid & 63;
  const int wid = tid >> 6;

  const int i = blockIdx.x - 128;  // 0..2047
  const int x = i & 7;             // XCD id (round-robin dispatch)
  const int k = i >> 3;            // 0..255
  const int mt = k >> 4;           // m-tile 0..15 (= t-chunk [mt*4, mt*4+4))
  const int kn = k & 15;           // n-slot
  const int tn = kn * 8 + x;       // 0..127
  if (tn >= 125) return;           // dummy (whole WG exits)
  const int tile_m = mt * 256;
  const int tile_n = tn * 256;
  const int wm = wid >> 2, wn = wid & 3;   // 2m x 4n waves, 128x64 each
  const int N = 32000, K = 1024;

  // ---- wait until decoder steps 0..mt*4+3 are complete in all clusters
  {
    u32 need = (u32)(mt * 4 + 4);
    if (tid < 4) {
      int guard = 0;
      while (__hip_atomic_load(&prog[tid], __ATOMIC_RELAXED,
                               __HIP_MEMORY_SCOPE_AGENT) < need) {
        __builtin_amdgcn_s_sleep(8);
        if (++guard > (1 << 22)) break;   // safety valve
      }
    }
    __syncthreads();
  }

  const int ldr = lane >> 2;
  const int lko = (lane & 3) * 8;
  const int l15 = lane & 15;
  const int g4 = lane >> 4;

  const size_t aBase = (size_t)tile_m * K;
  const size_t bBase = (size_t)tile_n * K;

  // stage one 256x32 A sub-tile + 256x32 B sub-tile: 4 GLD16/thread
  auto stg = [&](int buf, int k0) {
#pragma unroll
    for (int q = 0; q < 2; ++q) {
      int chk = wid * 2 + q;                 // 16 chunks of 16 rows
      int row = chk * 16 + ldr;
      GLD16(hsd + aBase + (size_t)row * K + k0 + lko, &lA[buf][chk * 512]);
    }
#pragma unroll
    for (int q = 0; q < 2; ++q) {
      int chk = wid * 2 + q;
      int row = chk * 16 + ldr;
      GLD16(wout + bBase + (size_t)row * K + k0 + lko, &lB[buf][chk * 512]);
    }
  };

  f32x4 acc[8][4];
#pragma unroll
  for (int i2 = 0; i2 < 8; ++i2)
#pragma unroll
    for (int j2 = 0; j2 < 4; ++j2) acc[i2][j2] = (f32x4)0.f;

  stg(0, 0);                           // prologue: tile 0 in flight

  const int NIT = K >> 5;              // 32
  for (int it = 0; it < NIT; ++it) {
    const int cur = it % 3;
    if (it + 1 < NIT) {
      stg((it + 1) % 3, (it + 1) * 32);
      asm volatile("s_waitcnt vmcnt(4)" ::: "memory");  // tile it landed
    } else {
      asm volatile("s_waitcnt vmcnt(0)" ::: "memory");  // last tile: drain
    }
    __builtin_amdgcn_s_barrier();
    short8 af[8], bf[4];
#pragma unroll
    for (int i2 = 0; i2 < 8; ++i2)
      af[i2] = *(const short8*)&lA[cur][(wm * 128 + i2 * 16 + l15) * 32 + g4 * 8];
#pragma unroll
    for (int j2 = 0; j2 < 4; ++j2)
      bf[j2] = *(const short8*)&lB[cur][(wn * 64 + j2 * 16 + l15) * 32 + g4 * 8];
#pragma unroll
    for (int i2 = 0; i2 < 8; ++i2)
#pragma unroll
      for (int j2 = 0; j2 < 4; ++j2)
        acc[i2][j2] = __builtin_amdgcn_mfma_f32_16x16x32_bf16(af[i2], bf[j2], acc[i2][j2], 0, 0, 0);
  }

#pragma unroll
  for (int i2 = 0; i2 < 8; ++i2) {
    int row0 = tile_m + wm * 128 + i2 * 16 + (g4 << 2);
#pragma unroll
    for (int j2 = 0; j2 < 4; ++j2) {
      int col = tile_n + wn * 64 + j2 * 16 + l15;
      float bv = b_out[col];
#pragma unroll
      for (int e = 0; e < 4; ++e) {
        int rr = row0 + e;                       // t-major row = t*64+b
        size_t o = (size_t)((rr & 63) * 64 + (rr >> 6)) * (size_t)N + col;
        __builtin_nontemporal_store(acc[i2][j2][e] + bv, &out[o]);
      }
    }
  }
}

// ---------------------------------------------------------------------------
// mean/logvar/latent + hd0 = [latent|cond_e] @ W_st^T + b_st -> bf16 h0.
__global__ __launch_bounds__(256) void latent_hd0_kernel(
    const float* hT, const float* Wm, const float* bm,
    const float* Wl, const float* bl, const float* Wst, const float* bst,
    const float* eps, const float* ce, u16* hb0) {
  __shared__ float red[64][4];
  __shared__ float ml[64];
  __shared__ float lat[40];
  int b = blockIdx.x;
  int tid = threadIdx.x;
  int o = tid >> 2, p = tid & 3;
  const float* w = (o < 32) ? (Wm + (size_t)o * 1024) : (Wl + (size_t)(o - 32) * 1024);
  const float* h = hT + (size_t)b * 1024;
  float s = 0.f;
  for (int k = p * 256; k < p * 256 + 256; ++k) s += h[k] * w[k];
  red[o][p] = s;
  __syncthreads();
  if (tid < 64) {
    float v = red[tid][0] + red[tid][1] + red[tid][2] + red[tid][3];
    v += (tid < 32) ? bm[tid] : bl[tid - 32];
    ml[tid] = v;
  }
  __syncthreads();
  if (tid < 32) lat[tid] = eps[b * 32 + tid] * __expf(0.5f * ml[32 + tid]) + ml[tid];
  if (tid >= 32 && tid < 40) lat[tid] = ce[b * 8 + (tid - 32)];
  __syncthreads();
  for (int hc = tid; hc < 1024; hc += 256) {
    float s2 = bst[hc];
    const float* wr = Wst + (size_t)hc * 40;
#pragma unroll
    for (int j = 0; j < 40; ++j) s2 += lat[j] * wr[j];
    hb0[b * 1024 + hc] = f2bf(s2);
  }
}

// ---------------------------------------------------------------------------
extern "C" void kernel_launch(void* const* d_in, const int* in_sizes, int n_in,
                              void* d_out, int out_size, void* d_ws, size_t ws_size,
                              hipStream_t stream) {
  const int*   input_word = (const int*)d_in[0];
  const int*   cond       = (const int*)d_in[1];
  const float* emb_N      = (const float*)d_in[2];
  const float* Wih_N      = (const float*)d_in[3];
  const float* Whh_N      = (const float*)d_in[4];
  const float* bih_N      = (const float*)d_in[5];
  const float* bhh_N      = (const float*)d_in[6];
  const float* emb_D      = (const float*)d_in[7];
  const float* Wih_D      = (const float*)d_in[8];
  const float* Whh_D      = (const float*)d_in[9];
  const float* bih_D      = (const float*)d_in[10];
  const float* bhh_D      = (const float*)d_in[11];
  const float* emb_cond   = (const float*)d_in[12];
  const float* W_mean     = (const float*)d_in[13];
  const float* b_mean     = (const float*)d_in[14];
  const float* W_logvar   = (const float*)d_in[15];
  const float* b_logvar   = (const float*)d_in[16];
  const float* W_st       = (const float*)d_in[17];
  const float* b_st       = (const float*)d_in[18];
  const float* W_out      = (const float*)d_in[19];
  const float* b_out      = (const float*)d_in[20];
  const float* eps        = (const float*)d_in[21];
  float* out = (float*)d_out;

  char* ws = (char*)d_ws;
  size_t off = 0;
  auto alloc = [&](size_t b) { size_t p = off; off += (b + 255) & ~(size_t)255; return p; };
  u16*   wihN = (u16*)(ws + alloc(4096ull * 1024 * 2));
  u16*   whhN = (u16*)(ws + alloc(4096ull * 1024 * 2));
  u16*   wihD = (u16*)(ws + alloc(4096ull * 1024 * 2));
  u16*   whhD = (u16*)(ws + alloc(4096ull * 1024 * 2));
  u16*   wout = (u16*)(ws + alloc(32000ull * 1024 * 2));
  u16*   Xe   = (u16*)(ws + alloc(4096ull * 1024 * 2));
  u16*   Xd   = (u16*)(ws + alloc(4096ull * 1024 * 2));
  float* Xp   = (float*)(ws + alloc(4096ull * 4096 * 4));   // enc (and dec fallback)
  u16*   hsd  = (u16*)(ws + alloc(4096ull * 1024 * 2));     // T-MAJOR [t*64+b][1024]
  u16*   hb   = (u16*)(ws + alloc(2ull * 64 * 1024 * 2));   // bf16 h dbuf
  float* hf   = (float*)(ws + alloc(64ull * 1024 * 4));     // fp32 h_T (encoder)
  float* biasN = (float*)(ws + alloc(4096 * 4));
  float* biasD = (float*)(ws + alloc(4096 * 4));
  float* ce    = (float*)(ws + alloc(64 * 8 * 4));
  u32*   bar   = (u32*)(ws + alloc(4096));
  // bar: enc arrive [0..127], dec arrive [256..383], dec prog [512..515],
  //      XpE done [768..783]
  size_t base_off = off;
  float* XpD2 = (float*)(ws + alloc(4096ull * 4096 * 4));   // dec Xp (fused path)
  if (base_off > ws_size) return;
  const bool fused = (off <= ws_size);
  float* XpD = fused ? XpD2 : Xp;

  // front-end: weights conv + prep + gathers + h0 init, one launch
  front_all<<<24854, 256, 0, stream>>>(Wih_N, wihN, Whh_N, whhN,
                                       Wih_D, wihD, Whh_D, whhD,
                                       cond, emb_cond,
                                       bih_N, bhh_N, bih_D, bhh_D,
                                       ce, biasN, biasD, bar,
                                       emb_N, emb_D, input_word, Xe, Xd, hb);

  if (fused) {
    // encoder LSTM + XpE producer + decoder-Xp GEMM + W_out conv, one launch
    enc_fused<<<1280, 512, 0, stream>>>(whhN, Xp, hb, hf, bar + 0, bar + 768,
                                        Xe, wihN, biasN,
                                        Xd, wihD, XpD, biasD, W_out, wout);
  } else {
    gemm_bt0<<<512, 512, 0, stream>>>(Xe, wihN, Xp, biasN, 4096, 1024);
    conv_wout<<<32000, 256, 0, stream>>>(W_out, wout);
    lstm_cluster<<<128, 512, 0, stream>>>(whhN, Xp, hb, hf, bar + 0);
  }
  // latent + decoder h0
  latent_hd0_kernel<<<64, 256, 0, stream>>>(hf, W_mean, b_mean, W_logvar, b_logvar,
                                            W_st, b_st, eps, ce, hb);
  if (!fused)
    gemm_bt0<<<512, 512, 0, stream>>>(Xd, wihD, XpD, biasD, 4096, 1024);
  // decoder LSTM + logits GEMM fused (256x256 tile, counted-vmcnt pipeline)
  dec_fused<<<2176, 512, 0, stream>>>(whhD, XpD, hb, hsd, bar + 256, bar + 512,
                                      wout, out, b_out);
}

// Round 25
// 888.707 us; speedup vs baseline: 1.1675x; 1.0023x over previous
//
#include <hip/hip_runtime.h>
#include <hip/hip_bf16.h>

typedef unsigned short u16;
typedef unsigned int   u32;
typedef unsigned long long u64;
typedef __attribute__((ext_vector_type(8))) short short8;   // 8 x bf16 (4 VGPRs)
typedef __attribute__((ext_vector_type(4))) float f32x4;

#define DEVINL static __device__ __forceinline__

// round-to-nearest-even f32 -> bf16
DEVINL u16 f2bf(float x) {
  u32 u = __float_as_uint(x);
  u32 r = (u + 0x7fffu + ((u >> 16) & 1u)) >> 16;
  return (u16)r;
}

// async global->LDS, 16B per lane. LDS dest = uniform base + lane*16.
#define GLD16(gp, lp) __builtin_amdgcn_global_load_lds(                     \
    (const __attribute__((address_space(1))) u32*)(gp),                     \
    (__attribute__((address_space(3))) u32*)(lp), 16, 0, 0)

// ---------------------------------------------------------------------------
// FRONT-END, one segmented launch: conv4 | prep | gatherE | gatherD | init.
__global__ __launch_bounds__(256) void front_all(
    const float* __restrict__ s0, u16* __restrict__ d0,
    const float* __restrict__ s1, u16* __restrict__ d1,
    const float* __restrict__ s2, u16* __restrict__ d2,
    const float* __restrict__ s3, u16* __restrict__ d3,
    const int* __restrict__ cond, const float* __restrict__ emb_cond,
    const float* __restrict__ bihN, const float* __restrict__ bhhN,
    const float* __restrict__ bihD, const float* __restrict__ bhhD,
    float* __restrict__ ce, float* __restrict__ biasN, float* __restrict__ biasD,
    u32* __restrict__ bar,
    const float* __restrict__ embN, const float* __restrict__ embD,
    const int* __restrict__ words, u16* __restrict__ Xe, u16* __restrict__ Xd,
    u16* __restrict__ hb0) {
  int blk = blockIdx.x;
  if (blk < 16384) {                       // ---- weight conversion (4x 4Kx1K)
    int p = blk >> 12, local = blk & 4095;
    const float* s = (p == 0) ? s0 : (p == 1) ? s1 : (p == 2) ? s2 : s3;
    u16*         d = (p == 0) ? d0 : (p == 1) ? d1 : (p == 2) ? d2 : d3;
    int i = local * 256 + threadIdx.x;
    float4 v = ((const float4*)s)[i];
    ushort4 o;
    o.x = f2bf(v.x); o.y = f2bf(v.y); o.z = f2bf(v.z); o.w = f2bf(v.w);
    ((ushort4*)d)[i] = o;
  } else if (blk < 16406) {                // ---- prep (ce, biases, barriers)
    int tid = (blk - 16384) * 256 + threadIdx.x;
    if (tid < 512) {
      int b = tid >> 3, j = tid & 7;
      ce[tid] = emb_cond[cond[b] * 8 + j];
    }
    int i = tid - 512;
    if (i >= 0 && i < 4096) {
      biasN[i] = bihN[i] + bhhN[i];
      biasD[i] = bihD[i] + bhhD[i];
    }
    int k = tid - 4608;
    if (k >= 0 && k < 1024) bar[k] = 0;
  } else if (blk < 24598) {                // ---- embedding gathers
    int dec = (blk >= 20502);
    int r = blk - (dec ? 20502 : 16406);   // r = t*64 + b
    int t = r >> 6, b = r & 63;
    int tok = dec ? ((t == 0) ? 0 : words[b * 64 + t - 1]) : words[b * 64 + t];
    const float* emb = dec ? embD : embN;
    u16* X = dec ? Xd : Xe;
    float4 v = ((const float4*)(emb + (size_t)tok * 1024))[threadIdx.x];
    ushort4 o;
    o.x = f2bf(v.x); o.y = f2bf(v.y); o.z = f2bf(v.z); o.w = f2bf(v.w);
    ((ushort4*)(X + (size_t)r * 1024))[threadIdx.x] = o;
  } else {                                 // ---- encoder h0
    int tid = (blk - 24598) * 256 + threadIdx.x;   // 64*1024
    int b = tid >> 10, col = tid & 1023;
    float v = (col >= 1016) ? emb_cond[cond[b] * 8 + (col - 1016)] : 0.f;
    hb0[tid] = f2bf(v);
  }
}

// standalone W_out conversion (fallback path only)
__global__ __launch_bounds__(256) void conv_wout(const float* __restrict__ s,
                                                 u16* __restrict__ d) {
  int i = blockIdx.x * 256 + threadIdx.x;
  float4 v = ((const float4*)s)[i];
  ushort4 o;
  o.x = f2bf(v.x); o.y = f2bf(v.y); o.z = f2bf(v.z); o.w = f2bf(v.w);
  ((ushort4*)d)[i] = o;
}

// ---------------------------------------------------------------------------
// GEMM body, MODE-0 style (n-fast + bijective XCD swizzle), 256x128 tile,
// BK=32, 512 threads = 8 waves (4m x 2n), double-buffered LDS (48KB).
DEVINL void gemm0_body(char* smemc, int bid, int nwg,
                       const u16* __restrict__ A, const u16* __restrict__ B,
                       float* __restrict__ C, const float* __restrict__ bias,
                       int N, int K) {
  u16 (*lA)[256 * 32] = (u16(*)[256 * 32])smemc;
  u16 (*lB)[128 * 32] = (u16(*)[128 * 32])(smemc + 32768);
  const int tid = threadIdx.x;
  const int lane = tid & 63;
  const int wid = tid >> 6;

  const int nn = N >> 7;
  const int wgid = (bid & 7) * (nwg >> 3) + (bid >> 3);
  const int tile_m = (wgid / nn) * 256;
  const int tile_n = (wgid % nn) * 128;
  const int wm = wid >> 1, wn = wid & 1;

  const int ldr = lane >> 2;
  const int lko = (lane & 3) * 8;
  const int l15 = lane & 15;
  const int g4 = lane >> 4;

  const size_t aBase = (size_t)tile_m * K;
  const size_t bBase = (size_t)tile_n * K;

  auto stage = [&](int buf, int k0) {
#pragma unroll
    for (int q = 0; q < 2; ++q) {
      int chk = wid * 2 + q;
      int row = chk * 16 + ldr;
      GLD16(A + aBase + (size_t)row * K + k0 + lko, &lA[buf][chk * 512]);
    }
    int row = wid * 16 + ldr;
    GLD16(B + bBase + (size_t)row * K + k0 + lko, &lB[buf][wid * 512]);
  };

  f32x4 acc[4][4];
#pragma unroll
  for (int i = 0; i < 4; ++i)
#pragma unroll
    for (int j = 0; j < 4; ++j) acc[i][j] = (f32x4)0.f;

  stage(0, 0);
  __syncthreads();

  const int NIT = K >> 5;
  for (int it = 0; it < NIT; ++it) {
    const int cur = it & 1;
    if (it + 1 < NIT) stage(cur ^ 1, (it + 1) * 32);
    short8 af[4], bf[4];
#pragma unroll
    for (int i = 0; i < 4; ++i)
      af[i] = *(const short8*)&lA[cur][(wm * 64 + i * 16 + l15) * 32 + g4 * 8];
#pragma unroll
    for (int j = 0; j < 4; ++j)
      bf[j] = *(const short8*)&lB[cur][(wn * 64 + j * 16 + l15) * 32 + g4 * 8];
#pragma unroll
    for (int i = 0; i < 4; ++i)
#pragma unroll
      for (int j = 0; j < 4; ++j)
        acc[i][j] = __builtin_amdgcn_mfma_f32_16x16x32_bf16(af[i], bf[j], acc[i][j], 0, 0, 0);
    __syncthreads();
  }

#pragma unroll
  for (int i = 0; i < 4; ++i) {
    int row0 = tile_m + wm * 64 + i * 16 + (g4 << 2);
#pragma unroll
    for (int j = 0; j < 4; ++j) {
      int col = tile_n + wn * 64 + j * 16 + l15;
      float bv = bias[col];
#pragma unroll
      for (int e = 0; e < 4; ++e)
        C[(size_t)(row0 + e) * (size_t)N + col] = acc[i][j][e] + bv;
    }
  }
}

// ---------------------------------------------------------------------------
// XpE PRODUCER: 128 blocks; block p owns n-panel (p&31) and walks m-tiles
// mt = r*4 + (p>>5), r=0..3 — t-chunks 0..3 complete after round one.
// NT stores (write-through) + vmcnt(0) + atomicAdd done[mt] (release).
DEVINL void xpe_producer(char* smemc, int p,
                         const u16* __restrict__ Xe, const u16* __restrict__ W,
                         float* __restrict__ Xp, const float* __restrict__ bias,
                         u32* __restrict__ done) {
  u16 (*lA)[256 * 32] = (u16(*)[256 * 32])smemc;
  u16 (*lB)[128 * 32] = (u16(*)[128 * 32])(smemc + 32768);
  const int tid = threadIdx.x;
  const int lane = tid & 63;
  const int wid = tid >> 6;
  const int n = p & 31, mq = p >> 5;
  const int wm = wid >> 1, wn = wid & 1;
  const int ldr = lane >> 2;
  const int lko = (lane & 3) * 8;
  const int l15 = lane & 15;
  const int g4 = lane >> 4;
  const int N = 4096, K = 1024;
  const int tile_n = n * 128;
  const size_t bBase = (size_t)tile_n * K;

  for (int r2 = 0; r2 < 4; ++r2) {
    const int mt = r2 * 4 + mq;
    const int tile_m = mt * 256;
    const size_t aBase = (size_t)tile_m * K;

    auto stage = [&](int buf, int k0) {
#pragma unroll
      for (int q = 0; q < 2; ++q) {
        int chk = wid * 2 + q;
        int row = chk * 16 + ldr;
        GLD16(Xe + aBase + (size_t)row * K + k0 + lko, &lA[buf][chk * 512]);
      }
      int row = wid * 16 + ldr;
      GLD16(W + bBase + (size_t)row * K + k0 + lko, &lB[buf][wid * 512]);
    };

    f32x4 acc[4][4];
#pragma unroll
    for (int i = 0; i < 4; ++i)
#pragma unroll
      for (int j = 0; j < 4; ++j) acc[i][j] = (f32x4)0.f;

    stage(0, 0);
    __syncthreads();
    const int NIT = K >> 5;
    for (int it = 0; it < NIT; ++it) {
      const int cur = it & 1;
      if (it + 1 < NIT) stage(cur ^ 1, (it + 1) * 32);
      short8 af[4], bf[4];
#pragma unroll
      for (int i = 0; i < 4; ++i)
        af[i] = *(const short8*)&lA[cur][(wm * 64 + i * 16 + l15) * 32 + g4 * 8];
#pragma unroll
      for (int j = 0; j < 4; ++j)
        bf[j] = *(const short8*)&lB[cur][(wn * 64 + j * 16 + l15) * 32 + g4 * 8];
#pragma unroll
      for (int i = 0; i < 4; ++i)
#pragma unroll
        for (int j = 0; j < 4; ++j)
          acc[i][j] = __builtin_amdgcn_mfma_f32_16x16x32_bf16(af[i], bf[j], acc[i][j], 0, 0, 0);
      __syncthreads();
    }

#pragma unroll
    for (int i = 0; i < 4; ++i) {
      int row0 = tile_m + wm * 64 + i * 16 + (g4 << 2);
#pragma unroll
      for (int j = 0; j < 4; ++j) {
        int col = tile_n + wn * 64 + j * 16 + l15;
        float bv = bias[col];
#pragma unroll
        for (int e = 0; e < 4; ++e)
          __builtin_nontemporal_store(acc[i][j][e] + bv,
                                      &Xp[(size_t)(row0 + e) * (size_t)N + col]);
      }
    }
    asm volatile("s_waitcnt vmcnt(0)" ::: "memory");   // NT stores at coh point
    __syncthreads();
    if (tid == 0)
      __hip_atomic_fetch_add(&done[mt], 1u, __ATOMIC_RELEASE,
                             __HIP_MEMORY_SCOPE_AGENT);
    __syncthreads();
  }
}

// ---------------------------------------------------------------------------
// CLUSTERED PERSISTENT LSTM body (proven skeleton). If prog != null
// (decoder): hs_out is T-MAJOR via packed-u32 agent-atomic stores; j==0 WG
// publishes prog[c] per step. If xpdone != null: gate each 4-step Xp
// prefetch window on done[chunk] == 32.
DEVINL void lstm_body(char* smemc, const u16* __restrict__ Whh,
                      const float* __restrict__ Xp, u16* __restrict__ hbuf,
                      u16* __restrict__ hs_out, float* __restrict__ hT_out,
                      u32* arrive, u32* prog, u32* xpdone, int wgi) {
  __builtin_amdgcn_s_setprio(2);
  char* smemA = smemc;
  float (*lg)[16][16] = (float(*)[16][16])(smemc + 32768);
  const int tid = threadIdx.x;      // 0..511
  const int lane = tid & 63;
  const int v = tid >> 6;           // wave 0..7
  const int gate = v >> 1;
  const int ch = v & 1;             // col-half of the WG's 32 cols
  const int c = wgi >> 5;           // cluster 0..3 (batch rows c*16..+16)
  const int j = wgi & 31;           // WG in cluster (cols j*32..+32)
  const int b0 = c * 16, col0 = j * 32;
  const int l15 = lane & 15, g4 = lane >> 4;

  // Whh fragments: loaded ONCE, live across all 64 steps (128 VGPRs)
  short8 breg[32];
  {
    const u16* Brow = Whh + (size_t)(gate * 1024 + col0 + ch * 16 + l15) * 1024
                          + g4 * 8;
#pragma unroll
    for (int kk = 0; kk < 32; ++kk)
      breg[kk] = *(const short8*)(Brow + kk * 32);
  }

  // cell mapping: 512 threads = 16 rows x 32 cols
  const int crow = tid >> 5, colw = tid & 31;
  const int bg = b0 + crow, cgl = col0 + colw;
  const int ch2 = colw >> 4, cw = colw & 15;
  float creg = 0.f;

  // prologue: gate on first Xp chunk, then prefetch t=0
  if (xpdone) {
    if (tid == 0) {
      int guard = 0;
      while (__hip_atomic_load(&xpdone[0], __ATOMIC_RELAXED,
                               __HIP_MEMORY_SCOPE_AGENT) < 32u) {
        __builtin_amdgcn_s_sleep(2);
        if (++guard > (1 << 22)) break;
      }
    }
    __syncthreads();
  }
  float xg0, xg1, xg2, xg3;
  {
    size_t xrow = (size_t)bg * 4096 + cgl;
    xg0 = __builtin_nontemporal_load(&Xp[xrow]);
    xg1 = __builtin_nontemporal_load(&Xp[xrow + 1024]);
    xg2 = __builtin_nontemporal_load(&Xp[xrow + 2048]);
    xg3 = __builtin_nontemporal_load(&Xp[xrow + 3072]);
  }

  for (int t = 0; t < 64; ++t) {
    const char* rbase = (const char*)(hbuf + (size_t)(t & 1) * 65536)
                      + (size_t)b0 * 2048;
    u32* wb32 = (u32*)(hbuf + (size_t)((t + 1) & 1) * 65536);

    // ---- stage h slab (16 rows x 1024 cols) -> swizzled LDS, atomic loads
#pragma unroll
    for (int q = 0; q < 4; ++q) {
      int g = q * 512 + tid;              // 16B chunk id 0..2047
      int row = g >> 7;                   // 0..15
      int cb = (g & 127) * 16;            // byte col in row
      const u64* src = (const u64*)(rbase + (size_t)row * 2048 + cb);
      u64 lo = __hip_atomic_load(src,     __ATOMIC_RELAXED, __HIP_MEMORY_SCOPE_AGENT);
      u64 hi = __hip_atomic_load(src + 1, __ATOMIC_RELAXED, __HIP_MEMORY_SCOPE_AGENT);
      u64* d = (u64*)(smemA + row * 2048 + (cb ^ ((row & 7) << 4)));
      d[0] = lo; d[1] = hi;
    }
    __syncthreads();

    // ---- 32 MFMAs/wave (4 chains), A from swizzled LDS, B from regs
    f32x4 a4[4] = {(f32x4)0.f, (f32x4)0.f, (f32x4)0.f, (f32x4)0.f};
#pragma unroll
    for (int kk = 0; kk < 32; ++kk) {
      int cb2 = kk * 64 + g4 * 16;
      const short8 a = *(const short8*)(smemA + l15 * 2048 + (cb2 ^ ((l15 & 7) << 4)));
      a4[kk & 3] = __builtin_amdgcn_mfma_f32_16x16x32_bf16(a, breg[kk], a4[kk & 3], 0, 0, 0);
    }
    f32x4 asum = a4[0] + a4[1] + a4[2] + a4[3];
    {
      int m = g4 * 4;
#pragma unroll
      for (int e = 0; e < 4; ++e) lg[v][m + e][l15] = asum[e];
    }
    __syncthreads();

    // ---- cell update: 1 cell per thread (uses prefetched xg)
    {
      float gi = lg[0 + ch2][crow][cw] + xg0;
      float gf = lg[2 + ch2][crow][cw] + xg1;
      float gg = lg[4 + ch2][crow][cw] + xg2;
      float go = lg[6 + ch2][crow][cw] + xg3;
      float si = 1.f / (1.f + __expf(-gi));
      float sf = 1.f / (1.f + __expf(-gf));
      float so = 1.f / (1.f + __expf(-go));
      float tg = tanhf(gg);
      float cn = sf * creg + si * tg;
      float hn = so * tanhf(cn);
      creg = cn;
      u16 h16 = f2bf(hn);
      u32 mine = h16;
      u32 other = (u32)__shfl_xor((int)mine, 1);
      if (!(colw & 1)) {
        u32 pk = mine | (other << 16);
        __hip_atomic_store(wb32 + (((size_t)bg * 1024 + cgl) >> 1), pk,
                           __ATOMIC_RELAXED, __HIP_MEMORY_SCOPE_AGENT);
        if (hs_out)   // t-major, write-through (consumed intra-dispatch)
          __hip_atomic_store((u32*)hs_out + ((((size_t)t * 64 + bg) * 1024 + cgl) >> 1),
                             pk, __ATOMIC_RELAXED, __HIP_MEMORY_SCOPE_AGENT);
      }
      if (hT_out && t == 63) hT_out[bg * 1024 + cgl] = hn;   // cross-kernel
    }

    // ---- gate next Xp chunk (fused-producer mode), prefetch, barrier
    if (t != 63) {
      if (xpdone && (((t + 1) & 3) == 0)) {
        if (tid == 0) {
          int guard = 0;
          while (__hip_atomic_load(&xpdone[(t + 1) >> 2], __ATOMIC_RELAXED,
                                   __HIP_MEMORY_SCOPE_AGENT) < 32u) {
            __builtin_amdgcn_s_sleep(2);
            if (++guard > (1 << 22)) break;
          }
        }
        __syncthreads();
      }
      {
        size_t xrow = (size_t)((t + 1) * 64 + bg) * 4096 + cgl;
        xg0 = __builtin_nontemporal_load(&Xp[xrow]);
        xg1 = __builtin_nontemporal_load(&Xp[xrow + 1024]);
        xg2 = __builtin_nontemporal_load(&Xp[xrow + 2048]);
        xg3 = __builtin_nontemporal_load(&Xp[xrow + 3072]);
      }
      u32 want = (u32)(t + 1);
      asm volatile("s_waitcnt vmcnt(0)" ::: "memory");   // drains h/hsd stores + Xp
      __syncthreads();
      if (tid == 0)
        __hip_atomic_store(&arrive[wgi], want, __ATOMIC_RELAXED,
                           __HIP_MEMORY_SCOPE_AGENT);
      if (tid < 32) {
        int guard = 0;
        while (__hip_atomic_load(&arrive[c * 32 + tid], __ATOMIC_RELAXED,
                                 __HIP_MEMORY_SCOPE_AGENT) < want) {
          __builtin_amdgcn_s_sleep(2);
          if (++guard > (1 << 20)) break;   // safety valve
        }
      }
      __syncthreads();
      if (prog && j == 0 && tid == 0)
        __hip_atomic_store(&prog[c], want, __ATOMIC_RELAXED,
                           __HIP_MEMORY_SCOPE_AGENT);
    }
  }

  // ---- final drain + publish prog = 64 (decoder only)
  if (prog) {
    asm volatile("s_waitcnt vmcnt(0)" ::: "memory");
    __syncthreads();
    if (tid == 0)
      __hip_atomic_store(&arrive[wgi], 64u, __ATOMIC_RELAXED,
                         __HIP_MEMORY_SCOPE_AGENT);
    if (j == 0) {
      if (tid < 32) {
        int guard = 0;
        while (__hip_atomic_load(&arrive[c * 32 + tid], __ATOMIC_RELAXED,
                                 __HIP_MEMORY_SCOPE_AGENT) < 64u) {
          __builtin_amdgcn_s_sleep(2);
          if (++guard > (1 << 20)) break;
        }
      }
      __syncthreads();
      if (tid == 0)
        __hip_atomic_store(&prog[c], 64u, __ATOMIC_RELAXED,
                           __HIP_MEMORY_SCOPE_AGENT);
    }
  }
  __builtin_amdgcn_s_setprio(0);
}

// ---------------------------------------------------------------------------
// Standalone LSTM wrapper (fallback path).
__global__ __launch_bounds__(512, 1) void lstm_cluster(
    const u16* __restrict__ Whh, const float* __restrict__ Xp,
    u16* __restrict__ hbuf, float* __restrict__ hT_out, u32* arrive) {
  __shared__ __align__(16) char smem[40960];
  lstm_body(smem, Whh, Xp, hbuf, nullptr, hT_out, arrive, nullptr, nullptr,
            blockIdx.x);
}

__global__ __launch_bounds__(512) void gemm_bt0(
    const u16* __restrict__ A, const u16* __restrict__ B,
    float* __restrict__ C, const float* __restrict__ bias, int N, int K) {
  __shared__ __align__(16) char smem[49152];
  gemm0_body(smem, blockIdx.x, gridDim.x, A, B, C, bias, N, K);
}

// Fused encoder: 0..127 = encoder LSTM (gated on XpE progress); 128..255 =
// XpE producer; 256..767 = XpD GEMM; 768..1279 = W_out conversion.
__global__ __launch_bounds__(512, 1) void enc_fused(
    const u16* __restrict__ whhN, float* __restrict__ XpE,
    u16* __restrict__ hbuf, float* __restrict__ hT_out, u32* arrive,
    u32* xpdone,
    const u16* __restrict__ Xe, const u16* __restrict__ wihN,
    const float* __restrict__ biasN,
    const u16* __restrict__ Xd, const u16* __restrict__ wihD,
    float* __restrict__ XpD, const float* __restrict__ biasD,
    const float* __restrict__ Wout, u16* __restrict__ wout) {
  __shared__ __align__(16) char smem[49152];
  if (blockIdx.x < 128) {
    lstm_body(smem, whhN, XpE, hbuf, nullptr, hT_out, arrive, nullptr, xpdone,
              blockIdx.x);
  } else if (blockIdx.x < 256) {
    xpe_producer(smem, blockIdx.x - 128, Xe, wihN, XpE, biasN, xpdone);
  } else if (blockIdx.x < 768) {
    gemm0_body(smem, blockIdx.x - 256, 512, Xd, wihD, XpD, biasD, 4096, 1024);
  } else {
    int tid0 = (blockIdx.x - 768) * 512 + threadIdx.x;
    for (int i = tid0; i < 8192000; i += 512 * 512) {
      float4 v = ((const float4*)Wout)[i];
      ushort4 o;
      o.x = f2bf(v.x); o.y = f2bf(v.y); o.z = f2bf(v.z); o.w = f2bf(v.w);
      ((ushort4*)wout)[i] = o;
    }
  }
}

// ---------------------------------------------------------------------------
// Fused decoder: blocks 0..127 = decoder LSTM (prio 2, t-major hsd + prog);
// blocks 128..2175 = logits GEMM, 256x256 tile, 4-BUFFER 2-DEEP counted-
// vmcnt pipeline: stage(k+2) -> vmcnt(8) -> s_barrier -> compute(k). Two
// tiles (8 GLD16/thread) stay in flight across each barrier, hiding the
// L2/L3 per-tile latency the r24 3-buffer/vmcnt(4) schedule exposed.
// Race-free (4 bufs): stage (k+2)%4 == (k-2)%4 (computed 2 barriers ago);
// concurrent compute (k-1)%4 differs by 3 mod 4. In-order vmem retirement:
// vmcnt(8) certifies tile k landed. Per-XCD n-partition, prog-gated.
__global__ __launch_bounds__(512, 1) void dec_fused(
    const u16* __restrict__ whhD, const float* __restrict__ XpD,
    u16* __restrict__ hbuf, u16* __restrict__ hsd, u32* arrive, u32* prog,
    const u16* __restrict__ wout, float* __restrict__ out,
    const float* __restrict__ b_out) {
  __shared__ __align__(16) char smem[131072];   // 4 x (16KB A + 16KB B)
  if (blockIdx.x < 128) {
    lstm_body(smem, whhD, XpD, hbuf, hsd, nullptr, arrive, prog, nullptr,
              blockIdx.x);
    return;
  }
  // ---- logits GEMM part, 256x256 tile
  u16 (*lA)[256 * 32] = (u16(*)[256 * 32])smem;            // 4 bufs
  u16 (*lB)[256 * 32] = (u16(*)[256 * 32])(smem + 65536);  // 4 bufs
  const int tid = threadIdx.x;
  const int lane = tid & 63;
  const int wid = tid >> 6;

  const int i = blockIdx.x - 128;  // 0..2047
  const int x = i & 7;             // XCD id (round-robin dispatch)
  const int k = i >> 3;            // 0..255
  const int mt = k >> 4;           // m-tile 0..15 (= t-chunk [mt*4, mt*4+4))
  const int kn = k & 15;           // n-slot
  const int tn = kn * 8 + x;       // 0..127
  if (tn >= 125) return;           // dummy (whole WG exits)
  const int tile_m = mt * 256;
  const int tile_n = tn * 256;
  const int wm = wid >> 2, wn = wid & 3;   // 2m x 4n waves, 128x64 each
  const int N = 32000, K = 1024;

  // ---- wait until decoder steps 0..mt*4+3 are complete in all clusters
  {
    u32 need = (u32)(mt * 4 + 4);
    if (tid < 4) {
      int guard = 0;
      while (__hip_atomic_load(&prog[tid], __ATOMIC_RELAXED,
                               __HIP_MEMORY_SCOPE_AGENT) < need) {
        __builtin_amdgcn_s_sleep(8);
        if (++guard > (1 << 22)) break;   // safety valve
      }
    }
    __syncthreads();
  }

  const int ldr = lane >> 2;
  const int lko = (lane & 3) * 8;
  const int l15 = lane & 15;
  const int g4 = lane >> 4;

  const size_t aBase = (size_t)tile_m * K;
  const size_t bBase = (size_t)tile_n * K;

  // stage one 256x32 A sub-tile + 256x32 B sub-tile: 4 GLD16/thread
  auto stg = [&](int buf, int k0) {
#pragma unroll
    for (int q = 0; q < 2; ++q) {
      int chk = wid * 2 + q;                 // 16 chunks of 16 rows
      int row = chk * 16 + ldr;
      GLD16(hsd + aBase + (size_t)row * K + k0 + lko, &lA[buf][chk * 512]);
    }
#pragma unroll
    for (int q = 0; q < 2; ++q) {
      int chk = wid * 2 + q;
      int row = chk * 16 + ldr;
      GLD16(wout + bBase + (size_t)row * K + k0 + lko, &lB[buf][chk * 512]);
    }
  };

  f32x4 acc[8][4];
#pragma unroll
  for (int i2 = 0; i2 < 8; ++i2)
#pragma unroll
    for (int j2 = 0; j2 < 4; ++j2) acc[i2][j2] = (f32x4)0.f;

  stg(0, 0);                           // prologue: tiles 0,1 in flight
  stg(1, 32);

  const int NIT = K >> 5;              // 32
  for (int it = 0; it < NIT; ++it) {
    const int cur = it & 3;
    if (it + 2 < NIT) {
      stg((it + 2) & 3, (it + 2) * 32);
      asm volatile("s_waitcnt vmcnt(8)" ::: "memory");  // tile it landed; 2 fly
    } else if (it + 1 < NIT) {
      asm volatile("s_waitcnt vmcnt(4)" ::: "memory");  // tile it landed; 1 flies
    } else {
      asm volatile("s_waitcnt vmcnt(0)" ::: "memory");  // last tile: drain
    }
    __builtin_amdgcn_s_barrier();
    short8 af[8], bf[4];
#pragma unroll
    for (int i2 = 0; i2 < 8; ++i2)
      af[i2] = *(const short8*)&lA[cur][(wm * 128 + i2 * 16 + l15) * 32 + g4 * 8];
#pragma unroll
    for (int j2 = 0; j2 < 4; ++j2)
      bf[j2] = *(const short8*)&lB[cur][(wn * 64 + j2 * 16 + l15) * 32 + g4 * 8];
#pragma unroll
    for (int i2 = 0; i2 < 8; ++i2)
#pragma unroll
      for (int j2 = 0; j2 < 4; ++j2)
        acc[i2][j2] = __builtin_amdgcn_mfma_f32_16x16x32_bf16(af[i2], bf[j2], acc[i2][j2], 0, 0, 0);
  }

#pragma unroll
  for (int i2 = 0; i2 < 8; ++i2) {
    int row0 = tile_m + wm * 128 + i2 * 16 + (g4 << 2);
#pragma unroll
    for (int j2 = 0; j2 < 4; ++j2) {
      int col = tile_n + wn * 64 + j2 * 16 + l15;
      float bv = b_out[col];
#pragma unroll
      for (int e = 0; e < 4; ++e) {
        int rr = row0 + e;                       // t-major row = t*64+b
        size_t o = (size_t)((rr & 63) * 64 + (rr >> 6)) * (size_t)N + col;
        __builtin_nontemporal_store(acc[i2][j2][e] + bv, &out[o]);
      }
    }
  }
}

// ---------------------------------------------------------------------------
// mean/logvar/latent + hd0 = [latent|cond_e] @ W_st^T + b_st -> bf16 h0.
__global__ __launch_bounds__(256) void latent_hd0_kernel(
    const float* hT, const float* Wm, const float* bm,
    const float* Wl, const float* bl, const float* Wst, const float* bst,
    const float* eps, const float* ce, u16* hb0) {
  __shared__ float red[64][4];
  __shared__ float ml[64];
  __shared__ float lat[40];
  int b = blockIdx.x;
  int tid = threadIdx.x;
  int o = tid >> 2, p = tid & 3;
  const float* w = (o < 32) ? (Wm + (size_t)o * 1024) : (Wl + (size_t)(o - 32) * 1024);
  const float* h = hT + (size_t)b * 1024;
  float s = 0.f;
  for (int k = p * 256; k < p * 256 + 256; ++k) s += h[k] * w[k];
  red[o][p] = s;
  __syncthreads();
  if (tid < 64) {
    float v = red[tid][0] + red[tid][1] + red[tid][2] + red[tid][3];
    v += (tid < 32) ? bm[tid] : bl[tid - 32];
    ml[tid] = v;
  }
  __syncthreads();
  if (tid < 32) lat[tid] = eps[b * 32 + tid] * __expf(0.5f * ml[32 + tid]) + ml[tid];
  if (tid >= 32 && tid < 40) lat[tid] = ce[b * 8 + (tid - 32)];
  __syncthreads();
  for (int hc = tid; hc < 1024; hc += 256) {
    float s2 = bst[hc];
    const float* wr = Wst + (size_t)hc * 40;
#pragma unroll
    for (int j = 0; j < 40; ++j) s2 += lat[j] * wr[j];
    hb0[b * 1024 + hc] = f2bf(s2);
  }
}

// ---------------------------------------------------------------------------
extern "C" void kernel_launch(void* const* d_in, const int* in_sizes, int n_in,
                              void* d_out, int out_size, void* d_ws, size_t ws_size,
                              hipStream_t stream) {
  const int*   input_word = (const int*)d_in[0];
  const int*   cond       = (const int*)d_in[1];
  const float* emb_N      = (const float*)d_in[2];
  const float* Wih_N      = (const float*)d_in[3];
  const float* Whh_N      = (const float*)d_in[4];
  const float* bih_N      = (const float*)d_in[5];
  const float* bhh_N      = (const float*)d_in[6];
  const float* emb_D      = (const float*)d_in[7];
  const float* Wih_D      = (const float*)d_in[8];
  const float* Whh_D      = (const float*)d_in[9];
  const float* bih_D      = (const float*)d_in[10];
  const float* bhh_D      = (const float*)d_in[11];
  const float* emb_cond   = (const float*)d_in[12];
  const float* W_mean     = (const float*)d_in[13];
  const float* b_mean     = (const float*)d_in[14];
  const float* W_logvar   = (const float*)d_in[15];
  const float* b_logvar   = (const float*)d_in[16];
  const float* W_st       = (const float*)d_in[17];
  const float* b_st       = (const float*)d_in[18];
  const float* W_out      = (const float*)d_in[19];
  const float* b_out      = (const float*)d_in[20];
  const float* eps        = (const float*)d_in[21];
  float* out = (float*)d_out;

  char* ws = (char*)d_ws;
  size_t off = 0;
  auto alloc = [&](size_t b) { size_t p = off; off += (b + 255) & ~(size_t)255; return p; };
  u16*   wihN = (u16*)(ws + alloc(4096ull * 1024 * 2));
  u16*   whhN = (u16*)(ws + alloc(4096ull * 1024 * 2));
  u16*   wihD = (u16*)(ws + alloc(4096ull * 1024 * 2));
  u16*   whhD = (u16*)(ws + alloc(4096ull * 1024 * 2));
  u16*   wout = (u16*)(ws + alloc(32000ull * 1024 * 2));
  u16*   Xe   = (u16*)(ws + alloc(4096ull * 1024 * 2));
  u16*   Xd   = (u16*)(ws + alloc(4096ull * 1024 * 2));
  float* Xp   = (float*)(ws + alloc(4096ull * 4096 * 4));   // enc (and dec fallback)
  u16*   hsd  = (u16*)(ws + alloc(4096ull * 1024 * 2));     // T-MAJOR [t*64+b][1024]
  u16*   hb   = (u16*)(ws + alloc(2ull * 64 * 1024 * 2));   // bf16 h dbuf
  float* hf   = (float*)(ws + alloc(64ull * 1024 * 4));     // fp32 h_T (encoder)
  float* biasN = (float*)(ws + alloc(4096 * 4));
  float* biasD = (float*)(ws + alloc(4096 * 4));
  float* ce    = (float*)(ws + alloc(64 * 8 * 4));
  u32*   bar   = (u32*)(ws + alloc(4096));
  // bar: enc arrive [0..127], dec arrive [256..383], dec prog [512..515],
  //      XpE done [768..783]
  size_t base_off = off;
  float* XpD2 = (float*)(ws + alloc(4096ull * 4096 * 4));   // dec Xp (fused path)
  if (base_off > ws_size) return;
  const bool fused = (off <= ws_size);
  float* XpD = fused ? XpD2 : Xp;

  // front-end: weights conv + prep + gathers + h0 init, one launch
  front_all<<<24854, 256, 0, stream>>>(Wih_N, wihN, Whh_N, whhN,
                                       Wih_D, wihD, Whh_D, whhD,
                                       cond, emb_cond,
                                       bih_N, bhh_N, bih_D, bhh_D,
                                       ce, biasN, biasD, bar,
                                       emb_N, emb_D, input_word, Xe, Xd, hb);

  if (fused) {
    // encoder LSTM + XpE producer + decoder-Xp GEMM + W_out conv, one launch
    enc_fused<<<1280, 512, 0, stream>>>(whhN, Xp, hb, hf, bar + 0, bar + 768,
                                        Xe, wihN, biasN,
                                        Xd, wihD, XpD, biasD, W_out, wout);
  } else {
    gemm_bt0<<<512, 512, 0, stream>>>(Xe, wihN, Xp, biasN, 4096, 1024);
    conv_wout<<<32000, 256, 0, stream>>>(W_out, wout);
    lstm_cluster<<<128, 512, 0, stream>>>(whhN, Xp, hb, hf, bar + 0);
  }
  // latent + decoder h0
  latent_hd0_kernel<<<64, 256, 0, stream>>>(hf, W_mean, b_mean, W_logvar, b_logvar,
                                            W_st, b_st, eps, ce, hb);
  if (!fused)
    gemm_bt0<<<512, 512, 0, stream>>>(Xd, wihD, XpD, biasD, 4096, 1024);
  // decoder LSTM + logits GEMM fused (256x256 tile, 4-buf 2-deep pipeline)
  dec_fused<<<2176, 512, 0, stream>>>(whhD, XpD, hb, hsd, bar + 256, bar + 512,
                                      wout, out, b_out);
}